// Round 1
// baseline (771.953 us; speedup 1.0000x reference)
//
#include <hip/hip_runtime.h>
#include <math.h>

#define NPn 30000
#define EPn 480000
#define NLl 48
#define ELl 144
#define Tn 96
#define NAn 11
#define Dn 256
#define N1 49
#define PHIn 1325
#define NEGf (-1000000000.0f)
#define NSTATES 97

// ---------------- pocket GCN ----------------

__global__ void k_deg(const int* __restrict__ dst, int* __restrict__ deg){
  int e = blockIdx.x*blockDim.x + threadIdx.x;
  if (e < EPn) atomicAdd(&deg[dst[e]], 1);
}

__global__ __launch_bounds__(1024) void k_scan(const int* __restrict__ deg, int* __restrict__ rowptr,
                                               int* __restrict__ cursor, float* __restrict__ dinv){
  __shared__ int sbuf[1024];
  __shared__ int scarry;
  if (threadIdx.x==0) scarry=0;
  __syncthreads();
  for (int base=0; base<NPn; base+=1024){
    int i = base + (int)threadIdx.x;
    int v = (i<NPn)? deg[i] : 0;
    sbuf[threadIdx.x] = v;
    __syncthreads();
    for (int off=1; off<1024; off<<=1){
      int t = (threadIdx.x>=(unsigned)off)? sbuf[threadIdx.x-off] : 0;
      __syncthreads();
      sbuf[threadIdx.x] += t;
      __syncthreads();
    }
    int incl = sbuf[threadIdx.x];
    int excl = incl - v;
    if (i<NPn){
      int rp = scarry + excl;
      rowptr[i]=rp; cursor[i]=rp;
      dinv[i] = rsqrtf((float)(deg[i]+1));
    }
    __syncthreads();
    if (threadIdx.x==1023) scarry += incl;
    __syncthreads();
  }
  if (threadIdx.x==0) rowptr[NPn]=scarry;
}

__global__ void k_fill(const int* __restrict__ src, const int* __restrict__ dst,
                       int* __restrict__ cursor, int* __restrict__ colidx){
  int e=blockIdx.x*blockDim.x+threadIdx.x;
  if (e<EPn){
    int pos=atomicAdd(&cursor[dst[e]],1);
    colidx[pos]=src[e];
  }
}

// a1[r][c] = (x_p[r] @ Wp1)[c] * dinv[r]
__global__ __launch_bounds__(256) void k_a1(const float* __restrict__ xp, const float* __restrict__ Wp1,
    const float* __restrict__ dinv, float* __restrict__ A){
  int r=blockIdx.x;
  int c=threadIdx.x;
  __shared__ float xr[15];
  if (threadIdx.x<15) xr[threadIdx.x]=xp[r*15+threadIdx.x];
  __syncthreads();
  float s=0.f;
  for (int kq=0;kq<15;kq++) s=fmaf(xr[kq],Wp1[kq*Dn+c],s);
  A[(size_t)r*Dn+c]=s*dinv[r];
}

// h1[d] = relu(dinv[d]*(sum_{s in in(d)} a1[s] + a1[d]) + bp1)
__global__ __launch_bounds__(256) void k_gather1(const int* __restrict__ rowptr, const int* __restrict__ colidx,
    const float* __restrict__ dinv, const float* __restrict__ A, const float* __restrict__ bp1,
    float* __restrict__ B){
  int d=blockIdx.x;
  int c=threadIdx.x;
  int b0=rowptr[d], b1=rowptr[d+1];
  float acc=A[(size_t)d*Dn+c];
  for (int e=b0;e<b1;e++){
    int s=colidx[e];
    acc += A[(size_t)s*Dn+c];
  }
  B[(size_t)d*Dn+c]=fmaxf(dinv[d]*acc+bp1[c],0.f);
}

// a2 = (h1 @ Wp2) * dinv[row]  (64x64x16 fp32 tile)
__global__ __launch_bounds__(256) void k_gemm(const float* __restrict__ Ain, const float* __restrict__ W,
    const float* __restrict__ dinv, float* __restrict__ Cc){
  __shared__ float As[16][64];
  __shared__ float Bs[16][64];
  int row0=blockIdx.x*64, col0=blockIdx.y*64;
  int tid=threadIdx.x;
  float acc[4][4];
  for (int i=0;i<4;i++) for (int j=0;j<4;j++) acc[i][j]=0.f;
  int la_r=(tid*4)>>4, la_k=(tid*4)&15;
  int lb_k=(tid*4)>>6, lb_n=(tid*4)&63;
  int txx=tid&15, tyy=tid>>4;
  for (int kk=0;kk<Dn;kk+=16){
    int gr=row0+la_r;
    float4 va = (gr<NPn)? *(const float4*)&Ain[(size_t)gr*Dn+kk+la_k] : make_float4(0.f,0.f,0.f,0.f);
    float4 vb = *(const float4*)&W[(size_t)(kk+lb_k)*Dn+col0+lb_n];
    As[la_k][la_r]=va.x; As[la_k+1][la_r]=va.y; As[la_k+2][la_r]=va.z; As[la_k+3][la_r]=va.w;
    *(float4*)&Bs[lb_k][lb_n]=vb;
    __syncthreads();
    for (int k2=0;k2<16;k2++){
      float4 a4=*(const float4*)&As[k2][tyy*4];
      float4 b4=*(const float4*)&Bs[k2][txx*4];
      acc[0][0]=fmaf(a4.x,b4.x,acc[0][0]); acc[0][1]=fmaf(a4.x,b4.y,acc[0][1]);
      acc[0][2]=fmaf(a4.x,b4.z,acc[0][2]); acc[0][3]=fmaf(a4.x,b4.w,acc[0][3]);
      acc[1][0]=fmaf(a4.y,b4.x,acc[1][0]); acc[1][1]=fmaf(a4.y,b4.y,acc[1][1]);
      acc[1][2]=fmaf(a4.y,b4.z,acc[1][2]); acc[1][3]=fmaf(a4.y,b4.w,acc[1][3]);
      acc[2][0]=fmaf(a4.z,b4.x,acc[2][0]); acc[2][1]=fmaf(a4.z,b4.y,acc[2][1]);
      acc[2][2]=fmaf(a4.z,b4.z,acc[2][2]); acc[2][3]=fmaf(a4.z,b4.w,acc[2][3]);
      acc[3][0]=fmaf(a4.w,b4.x,acc[3][0]); acc[3][1]=fmaf(a4.w,b4.y,acc[3][1]);
      acc[3][2]=fmaf(a4.w,b4.z,acc[3][2]); acc[3][3]=fmaf(a4.w,b4.w,acc[3][3]);
    }
    __syncthreads();
  }
  for (int i=0;i<4;i++){
    int gr=row0+tyy*4+i;
    if (gr<NPn){
      float dv=dinv[gr];
      for (int j=0;j<4;j++) Cc[(size_t)gr*Dn+col0+txx*4+j]=acc[i][j]*dv;
    }
  }
}

// z_pocket pre-mean accumulation: sum_e dinv[dst]*a2[src] + sum_d dinv[d]*a2[d]
__global__ __launch_bounds__(256) void k_red2(const int* __restrict__ srcp, const int* __restrict__ dstp,
    const float* __restrict__ dinv, const float* __restrict__ A, float* __restrict__ zp_acc){
  const int CH=250;
  int start=blockIdx.x*CH;
  int tid=threadIdx.x;
  float acc=0.f;
  for (int it=start; it<start+CH; it++){
    int row; float wgt;
    if (it<EPn){ row=srcp[it]; wgt=dinv[dstp[it]]; }
    else { int i=it-EPn; row=i; wgt=dinv[i]; }
    acc = fmaf(wgt, A[(size_t)row*Dn+tid], acc);
  }
  atomicAdd(&zp_acc[tid], acc);
}

__global__ void k_zpfin(const float* __restrict__ zp_acc, const float* __restrict__ bp2, float* __restrict__ z_pocket){
  int c=threadIdx.x;
  z_pocket[c]=zp_acc[c]*(1.0f/30000.0f)+bp2[c];
}

// ---------------- ligand GCN (mean only -> H_init z-part) ----------------

__global__ __launch_bounds__(1024) void k_lig(const float* __restrict__ xg, const int* __restrict__ lab,
    const int* __restrict__ srcl, const int* __restrict__ dstl,
    const float* __restrict__ Wl1, const float* __restrict__ bl1,
    const float* __restrict__ Wl2, const float* __restrict__ bl2,
    float* __restrict__ zl_mean){
  __shared__ float buf[NLl*Dn];
  __shared__ float sdinv[NLl];
  __shared__ int sdeg[NLl];
  __shared__ int ses[ELl+NLl], sed[ELl+NLl];
  int tid = threadIdx.x;
  if (tid<NLl) sdeg[tid]=1;
  __syncthreads();
  if (tid<ELl){ ses[tid]=srcl[tid]; sed[tid]=dstl[tid]; atomicAdd(&sdeg[dstl[tid]],1); }
  if (tid>=ELl && tid<ELl+NLl){ int r=tid-ELl; ses[tid]=r; sed[tid]=r; }
  __syncthreads();
  if (tid<NLl) sdinv[tid]=rsqrtf((float)sdeg[tid]);
  for (int i=tid;i<NLl*Dn;i+=1024) buf[i]=0.f;
  __syncthreads();
  // conv1 segment-sum over (edges + self loops), a1 computed on the fly
  if (tid<Dn){
    for (int e=0;e<ELl+NLl;e++){
      int s=ses[e], d=sed[e];
      float a1=0.f;
      for (int kq=0;kq<4;kq++) a1 = fmaf(xg[s*4+kq], Wl1[kq*Dn+tid], a1);
      a1 += Wl1[(4+lab[s])*Dn+tid];
      a1 *= sdinv[s];
      buf[d*Dn+tid] += a1;
    }
  }
  __syncthreads();
  for (int i=tid;i<NLl*Dn;i+=1024){
    int r=i>>8, c=i&255;
    buf[i] = fmaxf(sdinv[r]*buf[i] + bl1[c], 0.f);
  }
  __syncthreads();
  // t2 = h1 @ Wl2 (rows split across 4 groups of 256 threads)
  int c=tid&255, rg=tid>>8;
  float acc[12];
  for (int j=0;j<12;j++) acc[j]=0.f;
  for (int kk=0;kk<Dn;kk+=4){
    float w0=Wl2[kk*Dn+c], w1=Wl2[(kk+1)*Dn+c], w2=Wl2[(kk+2)*Dn+c], w3=Wl2[(kk+3)*Dn+c];
    for (int j=0;j<12;j++){
      int r=rg+4*j;
      float4 h=*(const float4*)&buf[r*Dn+kk];
      acc[j]=fmaf(h.x,w0,fmaf(h.y,w1,fmaf(h.z,w2,fmaf(h.w,w3,acc[j]))));
    }
  }
  __syncthreads();
  for (int j=0;j<12;j++){ int r=rg+4*j; buf[r*Dn+c]=acc[j]; }
  __syncthreads();
  // mean over rows of conv2 output (edge+self reduction)
  if (tid<Dn){
    float s2=0.f;
    for (int e=0;e<ELl+NLl;e++){
      int s=ses[e], d=sed[e];
      s2 = fmaf(sdinv[s]*sdinv[d], buf[s*Dn+tid], s2);
    }
    zl_mean[tid] = s2*(1.0f/48.0f) + bl2[tid];
  }
}

// ---------------- sequential control simulation (1 wave) ----------------

__global__ __launch_bounds__(64) void k_sim(const int* __restrict__ lab_in, const int* __restrict__ bfs_i,
    const int* __restrict__ bfs_b, int* __restrict__ lab_idx, float* __restrict__ lab_means,
    int* __restrict__ dirs, int* __restrict__ dird, float* __restrict__ m_arr, float* __restrict__ e_arr,
    int* __restrict__ rec, int* __restrict__ Sout){
  __shared__ float val[N1];
  __shared__ int closed[N1];
  __shared__ unsigned char adj[N1*N1];
  __shared__ int Q[Tn+1];
  __shared__ float mnou_sh[N1];
  int lane = threadIdx.x;
  if (lane < N1){
    int l = (lane<NLl)? lab_in[lane] : (NAn-1);
    lab_idx[lane]=l;
    float vv;
    switch(l){
      case 0: vv=4.f; break; case 1: vv=1.f; break; case 2: vv=3.f; break; case 3: vv=1.f; break;
      case 4: vv=2.f; break; case 5: vv=1.f; break; case 6: vv=5.f; break; case 7: vv=1.f; break;
      case 8: vv=6.f; break; case 9: vv=1.f; break; default: vv=1000.f; break;
    }
    val[lane]=vv; closed[lane]=0;
  }
  for (int i=lane;i<N1*N1;i+=64) adj[i]=0;
  for (int i=lane;i<=Tn;i+=64) Q[i]=0;
  if (lane < NAn){
    int cnt=0;
    for (int i=0;i<NLl;i++) cnt += (lab_in[i]==lane)?1:0;
    lab_means[lane] = ((float)cnt + ((lane==NAn-1)?1.f:0.f))*(1.0f/49.0f);  // mean of lab_v
    lab_means[NAn+lane] = (float)cnt*(1.0f/48.0f);                          // mean of lab_true
  }
  __syncthreads();
  if (lane==0){ Q[0]=bfs_i[0]; dirs[192]=bfs_i[0]; dird[192]=bfs_i[1]; }
  __syncthreads();
  int head=0, tail=1, ec=0, timec=0;
  for (int t=0;t<Tn;t++){
    int v = bfs_i[2*t+1];
    int bix = bfs_b[t];
    int active = (tail>head)?1:0;
    int u = Q[(head<=Tn)?head:Tn];
    float valu = val[u], valv = val[v];
    if (lane<N1){
      float base = ((val[lane]<1.0f) || (closed[lane]!=0) || (adj[u*N1+lane]!=0)) ? NEGf : 0.0f;
      if (lane==u) base=NEGf;
      float mnou = (valu<1.0f)? NEGf : base;
      float m = mnou;
      if (lane==v) m=0.0f;
      if (lane==NLl) m=0.0f;   // I_STOP
      m_arr[t*N1+lane]=m;
      mnou_sh[lane]=mnou;
    }
    __syncthreads();
    if (lane<4){
      float mnv = mnou_sh[v];
      float mv = fminf(valu, valv);
      float e;
      if (mv<=0.f) e=NEGf;
      else if (mv<=1.f) e=((lane==1)||(lane==2))?NEGf:0.f;
      else if (mv<=2.f) e=(lane==2)?NEGf:0.f;
      else e=0.f;
      if (mnv <= NEGf*0.5f) e=NEGf;
      if (lane==bix) e=0.f;
      e_arr[t*4+lane]=e;
    }
    int is_stop = (v==NLl)?1:0;
    int pop = active & is_stop;
    int doe = active & (is_stop^1);
    if (lane==0){
      rec[t]=u; rec[Tn+t]=v; rec[2*Tn+t]=bix; rec[3*Tn+t]=active; rec[4*Tn+t]=doe; rec[5*Tn+t]=timec;
    }
    __syncthreads();
    if (lane==0 && doe){
      if (tail<=Tn) Q[tail]=v;
      if (ec<192){ dirs[ec]=u; dird[ec]=v; dirs[ec+1]=v; dird[ec+1]=u; }
      float dec = (bix==0)?1.f:(bix==1)?2.f:(bix==2)?3.f:1.5f;
      val[u]-=dec; val[v]-=dec;
      adj[u*N1+v]=1; adj[v*N1+u]=1;
    }
    if (lane==0 && pop) closed[u]=1;
    head+=pop; tail+=doe; ec+=2*doe; timec+=doe;
    __syncthreads();
  }
  if (lane==0) Sout[0]=ec/2;
}

// ---------------- decoder GCN states (parallel over states) ----------------

__global__ __launch_bounds__(256) void k_d1(const int* __restrict__ Sp, const int* __restrict__ dirs,
    const int* __restrict__ dird, const int* __restrict__ lab_idx,
    const float* __restrict__ Wd1, const float* __restrict__ bd1,
    float* __restrict__ h1_st, float* __restrict__ dinv_st){
  int k = blockIdx.x;
  if (k > Sp[0]) return;
  __shared__ float acc[N1*Dn];
  __shared__ int sdeg[N1];
  __shared__ float sdinv[N1];
  __shared__ int se[192], sd[192];
  __shared__ int slab[N1];
  int tid=threadIdx.x;
  int cnt = (k==0)?1:(2*k);
  int base = (k==0)?192:0;
  if (tid<N1){ sdeg[tid]=1; slab[tid]=lab_idx[tid]; }
  __syncthreads();
  if (tid<cnt){ se[tid]=dirs[base+tid]; sd[tid]=dird[base+tid]; atomicAdd(&sdeg[sd[tid]],1); }
  __syncthreads();
  if (tid<N1) sdinv[tid]=rsqrtf((float)sdeg[tid]);
  for (int i=tid;i<N1*Dn;i+=256) acc[i]=0.f;
  __syncthreads();
  for (int e=0;e<cnt;e++){
    int s=se[e], d=sd[e];
    acc[d*Dn+tid] += Wd1[slab[s]*Dn+tid]*sdinv[s];
  }
  __syncthreads();
  float b=bd1[tid];
  for (int r=0;r<N1;r++){
    float a1 = Wd1[slab[r]*Dn+tid]*sdinv[r];
    float hv = sdinv[r]*(acc[r*Dn+tid]+a1) + b;
    h1_st[(size_t)(k*N1+r)*Dn+tid]=fmaxf(hv,0.f);
  }
  if (tid<N1) dinv_st[k*N1+tid]=sdinv[tid];
}

__global__ __launch_bounds__(1024) void k_d2a(const int* __restrict__ Sp, const float* __restrict__ Wd2,
    const float* __restrict__ h1_st, float* __restrict__ t2_st){
  int k=blockIdx.x;
  if (k>Sp[0]) return;
  __shared__ float hbuf[N1*Dn];
  int tid=threadIdx.x;
  for (int i=tid;i<N1*Dn;i+=1024) hbuf[i]=h1_st[(size_t)k*N1*Dn+i];
  __syncthreads();
  int c=tid&255, rg=tid>>8;
  int nr=(rg==0)?13:12;
  float acc[13];
  for (int j=0;j<13;j++) acc[j]=0.f;
  for (int kk=0;kk<Dn;kk+=4){
    float w0=Wd2[kk*Dn+c], w1=Wd2[(kk+1)*Dn+c], w2=Wd2[(kk+2)*Dn+c], w3=Wd2[(kk+3)*Dn+c];
    for (int j=0;j<nr;j++){
      int r=rg+4*j;
      float4 h=*(const float4*)&hbuf[r*Dn+kk];
      acc[j]=fmaf(h.x,w0,fmaf(h.y,w1,fmaf(h.z,w2,fmaf(h.w,w3,acc[j]))));
    }
  }
  for (int j=0;j<nr;j++){ int r=rg+4*j; t2_st[(size_t)(k*N1+r)*Dn+c]=acc[j]; }
}

__global__ __launch_bounds__(256) void k_d2b(const int* __restrict__ Sp, const int* __restrict__ dirs,
    const int* __restrict__ dird, const float* __restrict__ bd2, const float* __restrict__ t2_st,
    const float* __restrict__ dinv_st, float* __restrict__ z_st, float* __restrict__ h_mean){
  int k=blockIdx.x;
  if (k>Sp[0]) return;
  __shared__ float acc[N1*Dn];
  __shared__ float sdinv[N1];
  int tid=threadIdx.x;
  if (tid<N1) sdinv[tid]=dinv_st[k*N1+tid];
  for (int i=tid;i<N1*Dn;i+=256) acc[i]=0.f;
  __syncthreads();
  int cnt=(k==0)?1:(2*k);
  int base=(k==0)?192:0;
  for (int e=0;e<cnt;e++){
    int s=dirs[base+e], d=dird[base+e];
    acc[d*Dn+tid] += t2_st[(size_t)(k*N1+s)*Dn+tid]*sdinv[s];
  }
  __syncthreads();
  float b=bd2[tid];
  float msum=0.f;
  for (int r=0;r<N1;r++){
    float t2v=t2_st[(size_t)(k*N1+r)*Dn+tid];
    float z = sdinv[r]*(acc[r*Dn+tid]+t2v*sdinv[r]) + b;
    z_st[(size_t)k*N1*Dn + (size_t)r*Dn + tid]=z;
    msum+=z;
  }
  h_mean[k*Dn+tid]=msum*(1.0f/49.0f);
}

// ---------------- per-step logp contributions ----------------

__global__ __launch_bounds__(256) void k_c(const int* __restrict__ rec, const float* __restrict__ m_arr,
    const float* __restrict__ e_arr, const int* __restrict__ lab_idx, const float* __restrict__ lab_means,
    const float* __restrict__ z_st, const float* __restrict__ h_mean, const float* __restrict__ z_pocket,
    const float* __restrict__ zl_mean, const float* __restrict__ Wg, const float* __restrict__ Wh,
    const float* __restrict__ bh, float* __restrict__ out){
  const int t = blockIdx.x;
  if (!rec[3*Tn+t]) return;                 // inactive step: contributes 0
  const int u=rec[t], v=rec[Tn+t], bidx=rec[2*Tn+t], doe=rec[4*Tn+t], sidx=rec[5*Tn+t];
  const float timef=(float)sidx;
  __shared__ float g[N1];
  __shared__ float4 red[256];
  const int tid=threadIdx.x, lane=tid&63, wv=tid>>6;
  const float* zs = z_st + (size_t)sidx*N1*Dn;
  // g_i = z_v[i]·Wg[524:780] + Wg[780+lab_i] + m_i   (row-constant phi terms cancel in log-softmax)
  for (int r=wv; r<N1; r+=4){
    const float4 z4=*(const float4*)(zs + (size_t)r*Dn + lane*4);
    const float4 g4=*(const float4*)(Wg + 524 + lane*4);
    float p = z4.x*g4.x+z4.y*g4.y+z4.z*g4.z+z4.w*g4.w;
    for (int off=32; off>0; off>>=1) p += __shfl_down(p, off);
    if (lane==0) g[r] = p + Wg[780+lab_idx[r]] + m_arr[t*N1+r];
  }
  __syncthreads();
  // hlog = phi[v] @ Wh + bh + e  (full 1325-dot; 4 columns)
  float4 a=make_float4(0.f,0.f,0.f,0.f);
  if (doe){
    const int lu=lab_idx[u], lv=lab_idx[v];
    for (int rr=tid; rr<PHIn; rr+=256){
      float pv;
      if (rr==0) pv=timef;
      else if (rr<257)  pv=z_pocket[rr-1];
      else if (rr<513)  pv=zs[(size_t)u*Dn + (rr-257)];
      else if (rr<524)  pv=(lu==(rr-513))?1.f:0.f;
      else if (rr<780)  pv=zs[(size_t)v*Dn + (rr-524)];
      else if (rr<791)  pv=(lv==(rr-780))?1.f:0.f;
      else if (rr<1047) pv=h_mean[sidx*Dn + (rr-791)];
      else if (rr<1058) pv=lab_means[rr-1047];
      else if (rr<1314) pv=zl_mean[rr-1058];
      else              pv=lab_means[NAn + (rr-1314)];
      const float4 wr=*(const float4*)(Wh + rr*4);
      a.x=fmaf(pv,wr.x,a.x); a.y=fmaf(pv,wr.y,a.y); a.z=fmaf(pv,wr.z,a.z); a.w=fmaf(pv,wr.w,a.w);
    }
  }
  red[tid]=a;
  float gM=-INFINITY, gS=0.f;
  if (wv==0){
    float x=(lane<N1)? g[lane] : -INFINITY;
    gM=x;
    for (int off=32; off>0; off>>=1) gM=fmaxf(gM,__shfl_xor(gM,off));
    float ex=(lane<N1)? expf(x-gM):0.f;
    gS=ex;
    for (int off=32; off>0; off>>=1) gS+=__shfl_xor(gS,off);
  }
  for (int off=128; off>0; off>>=1){
    __syncthreads();
    if (tid<off){
      red[tid].x+=red[tid+off].x; red[tid].y+=red[tid+off].y;
      red[tid].z+=red[tid+off].z; red[tid].w+=red[tid+off].w;
    }
  }
  if (tid==0){
    float cg = g[v] - gM - logf(gS);
    float ch = 0.f;
    if (doe){
      float h0=red[0].x+bh[0]+e_arr[4*t+0];
      float h1=red[0].y+bh[1]+e_arr[4*t+1];
      float h2=red[0].z+bh[2]+e_arr[4*t+2];
      float h3=red[0].w+bh[3]+e_arr[4*t+3];
      float M=fmaxf(fmaxf(h0,h1),fmaxf(h2,h3));
      float se=expf(h0-M)+expf(h1-M)+expf(h2-M)+expf(h3-M);
      float hb=(bidx==0)?h0:(bidx==1)?h1:(bidx==2)?h2:h3;
      ch = hb - M - logf(se);
    }
    atomicAdd(out, cg+ch);
  }
}

// ---------------- launch ----------------

extern "C" void kernel_launch(void* const* d_in, const int* in_sizes, int n_in,
                              void* d_out, int out_size, void* d_ws, size_t ws_size,
                              hipStream_t stream){
  const float* x_p      =(const float*)d_in[0];
  const int*   src_p    =(const int*)d_in[1];
  const int*   dst_p    =(const int*)d_in[2];
  const float* x_l_geom =(const float*)d_in[3];
  const int*   x_l_label=(const int*)d_in[4];
  const int*   src_l    =(const int*)d_in[5];
  const int*   dst_l    =(const int*)d_in[6];
  const int*   bfs_index=(const int*)d_in[7];
  const int*   bfs_bond =(const int*)d_in[8];
  const float* Wp1=(const float*)d_in[9];
  const float* bp1=(const float*)d_in[10];
  const float* Wp2=(const float*)d_in[11];
  const float* bp2=(const float*)d_in[12];
  const float* Wl1=(const float*)d_in[13];
  const float* bl1=(const float*)d_in[14];
  const float* Wl2=(const float*)d_in[15];
  const float* bl2=(const float*)d_in[16];
  const float* Wd1=(const float*)d_in[17];
  const float* bd1=(const float*)d_in[18];
  const float* Wd2=(const float*)d_in[19];
  const float* bd2=(const float*)d_in[20];
  // d_in[21] Wf, d_in[22] bf: dead (pre-scan logp never enters carry)
  const float* Wg =(const float*)d_in[23];
  // d_in[24] bg: cancels in log-softmax
  const float* Wh =(const float*)d_in[25];
  const float* bh =(const float*)d_in[26];

  char* w=(char*)d_ws;
  size_t off=0;
  auto alloc=[&](size_t bytes)->char*{ char* p=w+off; off=(off+bytes+255)&~((size_t)255); return p; };
  float* A      =(float*)alloc((size_t)NPn*Dn*4);       // a1 then a2
  float* B      =(float*)alloc((size_t)NPn*Dn*4);       // h1
  int*   deg    =(int*)alloc((size_t)NPn*4);
  float* dinvp  =(float*)alloc((size_t)NPn*4);
  int*   rowptr =(int*)alloc((size_t)(NPn+1)*4);
  int*   cursor =(int*)alloc((size_t)NPn*4);
  int*   colidx =(int*)alloc((size_t)EPn*4);
  float* zp_acc =(float*)alloc(Dn*4);
  float* z_pocket=(float*)alloc(Dn*4);
  float* zl_mean=(float*)alloc(Dn*4);
  float* h1_st  =(float*)alloc((size_t)NSTATES*N1*Dn*4);
  float* t2_st  =(float*)alloc((size_t)NSTATES*N1*Dn*4);
  float* z_st   =(float*)alloc((size_t)NSTATES*N1*Dn*4);
  float* h_mean =(float*)alloc((size_t)NSTATES*Dn*4);
  float* dinv_st=(float*)alloc((size_t)NSTATES*N1*4);
  float* m_arr  =(float*)alloc((size_t)Tn*N1*4);
  float* e_arr  =(float*)alloc((size_t)Tn*4*4);
  int*   rec    =(int*)alloc((size_t)6*Tn*4);
  int*   dirs   =(int*)alloc(194*4);
  int*   dird   =(int*)alloc(194*4);
  int*   lab_idx=(int*)alloc(N1*4);
  float* lab_means=(float*)alloc(2*NAn*4);
  int*   Sval   =(int*)alloc(4);
  (void)in_sizes;(void)n_in;(void)ws_size;

  hipMemsetAsync(deg,0,(size_t)NPn*4,stream);
  hipMemsetAsync(zp_acc,0,Dn*4,stream);
  hipMemsetAsync(d_out,0,(size_t)out_size*sizeof(float),stream);

  // pocket GCN
  k_deg<<<EPn/256,256,0,stream>>>(dst_p,deg);
  k_scan<<<1,1024,0,stream>>>(deg,rowptr,cursor,dinvp);
  k_fill<<<EPn/256,256,0,stream>>>(src_p,dst_p,cursor,colidx);
  k_a1<<<NPn,256,0,stream>>>(x_p,Wp1,dinvp,A);
  k_gather1<<<NPn,256,0,stream>>>(rowptr,colidx,dinvp,A,bp1,B);
  dim3 gg((NPn+63)/64, Dn/64);
  k_gemm<<<gg,256,0,stream>>>(B,Wp2,dinvp,A);
  k_red2<<<2040,256,0,stream>>>(src_p,dst_p,dinvp,A,zp_acc);
  k_zpfin<<<1,256,0,stream>>>(zp_acc,bp2,z_pocket);
  // ligand GCN (H_init)
  k_lig<<<1,1024,0,stream>>>(x_l_geom,x_l_label,src_l,dst_l,Wl1,bl1,Wl2,bl2,zl_mean);
  // sequential control sim
  k_sim<<<1,64,0,stream>>>(x_l_label,bfs_index,bfs_bond,lab_idx,lab_means,dirs,dird,m_arr,e_arr,rec,Sval);
  // decoder GCN states
  k_d1<<<NSTATES,256,0,stream>>>(Sval,dirs,dird,lab_idx,Wd1,bd1,h1_st,dinv_st);
  k_d2a<<<NSTATES,1024,0,stream>>>(Sval,Wd2,h1_st,t2_st);
  k_d2b<<<NSTATES,256,0,stream>>>(Sval,dirs,dird,bd2,t2_st,dinv_st,z_st,h_mean);
  // logp
  k_c<<<Tn,256,0,stream>>>(rec,m_arr,e_arr,lab_idx,lab_means,z_st,h_mean,z_pocket,zl_mean,Wg,Wh,bh,(float*)d_out);
}

// Round 2
// 458.606 us; speedup vs baseline: 1.6833x; 1.6833x over previous
//
#include <hip/hip_runtime.h>
#include <math.h>

#define NPn 30000
#define EPn 480000
#define NLl 48
#define ELl 144
#define Tn 96
#define NAn 11
#define Dn 256
#define N1 49
#define PHIn 1325
#define NEGf (-1000000000.0f)
#define NSTATES 97
#define CHN 125

// ---------------- pocket GCN (collapsed) ----------------

__global__ void k_deg(const int* __restrict__ dst, int* __restrict__ deg){
  int e = blockIdx.x*blockDim.x + threadIdx.x;
  if (e < EPn) atomicAdd(&deg[dst[e]], 1);
}

__global__ void k_dinv(const int* __restrict__ deg, float* __restrict__ dinv){
  int i = blockIdx.x*blockDim.x + threadIdx.x;
  if (i < NPn) dinv[i] = rsqrtf((float)(deg[i]+1));
}

__global__ void k_odegw(const int* __restrict__ src, const int* __restrict__ dst,
                        const float* __restrict__ dinv, float* __restrict__ odegw){
  int e = blockIdx.x*blockDim.x + threadIdx.x;
  if (e < EPn) atomicAdd(&odegw[src[e]], dinv[dst[e]]);
}

// xagg[d][c] = sum over in-edges of x_p[s][c]*dinv[s]   (15-wide, padded to 16)
__global__ void k_xagg(const int* __restrict__ src, const int* __restrict__ dst,
                       const float* __restrict__ xp, const float* __restrict__ dinv,
                       float* __restrict__ xagg){
  int g = blockIdx.x*blockDim.x + threadIdx.x;
  int e = g>>4, c = g&15;
  if (e < EPn && c < 15){
    int s = src[e];
    atomicAdd(&xagg[dst[e]*16+c], xp[s*15+c]*dinv[s]);
  }
}

// fused: h1[s] = relu(dinv[s]*((xagg[s]+x'[s]) @ Wp1) + bp1); zr += coef[s]*h1[s]
// coef[s] = dinv[s]*(odegw[s]+dinv[s]);  h1 never materialized.
__global__ __launch_bounds__(256) void k_fuse(const float* __restrict__ xp, const float* __restrict__ xagg,
    const float* __restrict__ dinv, const float* __restrict__ odegw,
    const float* __restrict__ Wp1, const float* __restrict__ bp1, float* __restrict__ zr){
  __shared__ float sx[CHN][16];   // (xagg + x'[s]) * dinv[s]  (pre-scaled by dest dinv)
  __shared__ float sc[CHN];
  int tid = threadIdx.x;
  int base = blockIdx.x*CHN;
  float wcol[15];
  for (int k=0;k<15;k++) wcol[k]=Wp1[k*Dn+tid];
  float b = bp1[tid];
  for (int i=tid;i<CHN*16;i+=256){
    int n = base+(i>>4), c = i&15;
    float v = 0.f;
    if (n<NPn && c<15){
      float dv = dinv[n];
      v = (xagg[n*16+c] + xp[n*15+c]*dv)*dv;
    }
    sx[i>>4][i&15]=v;
  }
  for (int i=tid;i<CHN;i+=256){
    int n = base+i;
    sc[i] = (n<NPn)? dinv[n]*(odegw[n]+dinv[n]) : 0.f;
  }
  __syncthreads();
  float acc = 0.f;
  int lim = (NPn-base < CHN)? (NPn-base) : CHN;
  for (int i=0;i<lim;i++){
    float d0 = b;
    for (int k=0;k<15;k++) d0 = fmaf(sx[i][k], wcol[k], d0);
    acc = fmaf(sc[i], fmaxf(d0,0.f), acc);
  }
  atomicAdd(&zr[tid], acc);
}

// z_pocket = (zr/N) @ Wp2 + bp2
__global__ void k_zfin(const float* __restrict__ zr, const float* __restrict__ Wp2,
                       const float* __restrict__ bp2, float* __restrict__ z_pocket){
  __shared__ float sr[Dn];
  int tid=threadIdx.x;
  sr[tid]=zr[tid]*(1.0f/30000.0f);
  __syncthreads();
  float a=0.f;
  for (int k=0;k<Dn;k++) a=fmaf(sr[k],Wp2[(size_t)k*Dn+tid],a);
  z_pocket[tid]=a+bp2[tid];
}

// ---------------- ligand GCN (mean only -> H_init z-part) ----------------

__global__ __launch_bounds__(1024) void k_lig(const float* __restrict__ xg, const int* __restrict__ lab,
    const int* __restrict__ srcl, const int* __restrict__ dstl,
    const float* __restrict__ Wl1, const float* __restrict__ bl1,
    const float* __restrict__ Wl2, const float* __restrict__ bl2,
    float* __restrict__ zl_mean){
  __shared__ float buf[NLl*Dn];
  __shared__ float sdinv[NLl];
  __shared__ int sdeg[NLl];
  __shared__ int ses[ELl+NLl], sed[ELl+NLl];
  int tid = threadIdx.x;
  if (tid<NLl) sdeg[tid]=1;
  __syncthreads();
  if (tid<ELl){ ses[tid]=srcl[tid]; sed[tid]=dstl[tid]; atomicAdd(&sdeg[dstl[tid]],1); }
  if (tid>=ELl && tid<ELl+NLl){ int r=tid-ELl; ses[tid]=r; sed[tid]=r; }
  __syncthreads();
  if (tid<NLl) sdinv[tid]=rsqrtf((float)sdeg[tid]);
  for (int i=tid;i<NLl*Dn;i+=1024) buf[i]=0.f;
  __syncthreads();
  if (tid<Dn){
    for (int e=0;e<ELl+NLl;e++){
      int s=ses[e], d=sed[e];
      float a1=0.f;
      for (int kq=0;kq<4;kq++) a1 = fmaf(xg[s*4+kq], Wl1[kq*Dn+tid], a1);
      a1 += Wl1[(4+lab[s])*Dn+tid];
      a1 *= sdinv[s];
      buf[d*Dn+tid] += a1;
    }
  }
  __syncthreads();
  for (int i=tid;i<NLl*Dn;i+=1024){
    int r=i>>8, c=i&255;
    buf[i] = fmaxf(sdinv[r]*buf[i] + bl1[c], 0.f);
  }
  __syncthreads();
  int c=tid&255, rg=tid>>8;
  float acc[12];
  for (int j=0;j<12;j++) acc[j]=0.f;
  for (int kk=0;kk<Dn;kk+=4){
    float w0=Wl2[kk*Dn+c], w1=Wl2[(kk+1)*Dn+c], w2=Wl2[(kk+2)*Dn+c], w3=Wl2[(kk+3)*Dn+c];
    for (int j=0;j<12;j++){
      int r=rg+4*j;
      float4 h=*(const float4*)&buf[r*Dn+kk];
      acc[j]=fmaf(h.x,w0,fmaf(h.y,w1,fmaf(h.z,w2,fmaf(h.w,w3,acc[j]))));
    }
  }
  __syncthreads();
  for (int j=0;j<12;j++){ int r=rg+4*j; buf[r*Dn+c]=acc[j]; }
  __syncthreads();
  if (tid<Dn){
    float s2=0.f;
    for (int e=0;e<ELl+NLl;e++){
      int s=ses[e], d=sed[e];
      s2 = fmaf(sdinv[s]*sdinv[d], buf[s*Dn+tid], s2);
    }
    zl_mean[tid] = s2*(1.0f/48.0f) + bl2[tid];
  }
}

// ---------------- sequential control simulation (1 wave) ----------------

__global__ __launch_bounds__(64) void k_sim(const int* __restrict__ lab_in, const int* __restrict__ bfs_i,
    const int* __restrict__ bfs_b, int* __restrict__ lab_idx, float* __restrict__ lab_means,
    int* __restrict__ dirs, int* __restrict__ dird, float* __restrict__ m_arr, float* __restrict__ e_arr,
    int* __restrict__ rec, int* __restrict__ Sout){
  __shared__ float val[N1];
  __shared__ int closed[N1];
  __shared__ unsigned char adj[N1*N1];
  __shared__ int Q[Tn+1];
  __shared__ float mnou_sh[N1];
  int lane = threadIdx.x;
  if (lane < N1){
    int l = (lane<NLl)? lab_in[lane] : (NAn-1);
    lab_idx[lane]=l;
    float vv;
    switch(l){
      case 0: vv=4.f; break; case 1: vv=1.f; break; case 2: vv=3.f; break; case 3: vv=1.f; break;
      case 4: vv=2.f; break; case 5: vv=1.f; break; case 6: vv=5.f; break; case 7: vv=1.f; break;
      case 8: vv=6.f; break; case 9: vv=1.f; break; default: vv=1000.f; break;
    }
    val[lane]=vv; closed[lane]=0;
  }
  for (int i=lane;i<N1*N1;i+=64) adj[i]=0;
  for (int i=lane;i<=Tn;i+=64) Q[i]=0;
  if (lane < NAn){
    int cnt=0;
    for (int i=0;i<NLl;i++) cnt += (lab_in[i]==lane)?1:0;
    lab_means[lane] = ((float)cnt + ((lane==NAn-1)?1.f:0.f))*(1.0f/49.0f);
    lab_means[NAn+lane] = (float)cnt*(1.0f/48.0f);
  }
  __syncthreads();
  if (lane==0){ Q[0]=bfs_i[0]; dirs[192]=bfs_i[0]; dird[192]=bfs_i[1]; }
  __syncthreads();
  int head=0, tail=1, ec=0, timec=0;
  for (int t=0;t<Tn;t++){
    int v = bfs_i[2*t+1];
    int bix = bfs_b[t];
    int active = (tail>head)?1:0;
    int u = Q[(head<=Tn)?head:Tn];
    float valu = val[u], valv = val[v];
    if (lane<N1){
      float base = ((val[lane]<1.0f) || (closed[lane]!=0) || (adj[u*N1+lane]!=0)) ? NEGf : 0.0f;
      if (lane==u) base=NEGf;
      float mnou = (valu<1.0f)? NEGf : base;
      float m = mnou;
      if (lane==v) m=0.0f;
      if (lane==NLl) m=0.0f;
      m_arr[t*N1+lane]=m;
      mnou_sh[lane]=mnou;
    }
    __syncthreads();
    if (lane<4){
      float mnv = mnou_sh[v];
      float mv = fminf(valu, valv);
      float e;
      if (mv<=0.f) e=NEGf;
      else if (mv<=1.f) e=((lane==1)||(lane==2))?NEGf:0.f;
      else if (mv<=2.f) e=(lane==2)?NEGf:0.f;
      else e=0.f;
      if (mnv <= NEGf*0.5f) e=NEGf;
      if (lane==bix) e=0.f;
      e_arr[t*4+lane]=e;
    }
    int is_stop = (v==NLl)?1:0;
    int pop = active & is_stop;
    int doe = active & (is_stop^1);
    if (lane==0){
      rec[t]=u; rec[Tn+t]=v; rec[2*Tn+t]=bix; rec[3*Tn+t]=active; rec[4*Tn+t]=doe; rec[5*Tn+t]=timec;
    }
    __syncthreads();
    if (lane==0 && doe){
      if (tail<=Tn) Q[tail]=v;
      if (ec<192){ dirs[ec]=u; dird[ec]=v; dirs[ec+1]=v; dird[ec+1]=u; }
      float dec = (bix==0)?1.f:(bix==1)?2.f:(bix==2)?3.f:1.5f;
      val[u]-=dec; val[v]-=dec;
      adj[u*N1+v]=1; adj[v*N1+u]=1;
    }
    if (lane==0 && pop) closed[u]=1;
    head+=pop; tail+=doe; ec+=2*doe; timec+=doe;
    __syncthreads();
  }
  if (lane==0) Sout[0]=ec/2;
}

// ---------------- decoder GCN states (parallel over states) ----------------

__global__ __launch_bounds__(256) void k_d1(const int* __restrict__ Sp, const int* __restrict__ dirs,
    const int* __restrict__ dird, const int* __restrict__ lab_idx,
    const float* __restrict__ Wd1, const float* __restrict__ bd1,
    float* __restrict__ h1_st, float* __restrict__ dinv_st){
  int k = blockIdx.x;
  if (k > Sp[0]) return;
  __shared__ float acc[N1*Dn];
  __shared__ int sdeg[N1];
  __shared__ float sdinv[N1];
  __shared__ int se[192], sd[192];
  __shared__ int slab[N1];
  int tid=threadIdx.x;
  int cnt = (k==0)?1:(2*k);
  int base = (k==0)?192:0;
  if (tid<N1){ sdeg[tid]=1; slab[tid]=lab_idx[tid]; }
  __syncthreads();
  if (tid<cnt){ se[tid]=dirs[base+tid]; sd[tid]=dird[base+tid]; atomicAdd(&sdeg[sd[tid]],1); }
  __syncthreads();
  if (tid<N1) sdinv[tid]=rsqrtf((float)sdeg[tid]);
  for (int i=tid;i<N1*Dn;i+=256) acc[i]=0.f;
  __syncthreads();
  for (int e=0;e<cnt;e++){
    int s=se[e], d=sd[e];
    acc[d*Dn+tid] += Wd1[slab[s]*Dn+tid]*sdinv[s];
  }
  __syncthreads();
  float b=bd1[tid];
  for (int r=0;r<N1;r++){
    float a1 = Wd1[slab[r]*Dn+tid]*sdinv[r];
    float hv = sdinv[r]*(acc[r*Dn+tid]+a1) + b;
    h1_st[(size_t)(k*N1+r)*Dn+tid]=fmaxf(hv,0.f);
  }
  if (tid<N1) dinv_st[k*N1+tid]=sdinv[tid];
}

__global__ __launch_bounds__(1024) void k_d2a(const int* __restrict__ Sp, const float* __restrict__ Wd2,
    const float* __restrict__ h1_st, float* __restrict__ t2_st){
  int k=blockIdx.x;
  if (k>Sp[0]) return;
  __shared__ float hbuf[N1*Dn];
  int tid=threadIdx.x;
  for (int i=tid;i<N1*Dn;i+=1024) hbuf[i]=h1_st[(size_t)k*N1*Dn+i];
  __syncthreads();
  int c=tid&255, rg=tid>>8;
  int nr=(rg==0)?13:12;
  float acc[13];
  for (int j=0;j<13;j++) acc[j]=0.f;
  for (int kk=0;kk<Dn;kk+=4){
    float w0=Wd2[kk*Dn+c], w1=Wd2[(kk+1)*Dn+c], w2=Wd2[(kk+2)*Dn+c], w3=Wd2[(kk+3)*Dn+c];
    for (int j=0;j<nr;j++){
      int r=rg+4*j;
      float4 h=*(const float4*)&hbuf[r*Dn+kk];
      acc[j]=fmaf(h.x,w0,fmaf(h.y,w1,fmaf(h.z,w2,fmaf(h.w,w3,acc[j]))));
    }
  }
  for (int j=0;j<nr;j++){ int r=rg+4*j; t2_st[(size_t)(k*N1+r)*Dn+c]=acc[j]; }
}

__global__ __launch_bounds__(256) void k_d2b(const int* __restrict__ Sp, const int* __restrict__ dirs,
    const int* __restrict__ dird, const float* __restrict__ bd2, const float* __restrict__ t2_st,
    const float* __restrict__ dinv_st, float* __restrict__ z_st, float* __restrict__ h_mean){
  int k=blockIdx.x;
  if (k>Sp[0]) return;
  __shared__ float acc[N1*Dn];
  __shared__ float sdinv[N1];
  int tid=threadIdx.x;
  if (tid<N1) sdinv[tid]=dinv_st[k*N1+tid];
  for (int i=tid;i<N1*Dn;i+=256) acc[i]=0.f;
  __syncthreads();
  int cnt=(k==0)?1:(2*k);
  int base=(k==0)?192:0;
  for (int e=0;e<cnt;e++){
    int s=dirs[base+e], d=dird[base+e];
    acc[d*Dn+tid] += t2_st[(size_t)(k*N1+s)*Dn+tid]*sdinv[s];
  }
  __syncthreads();
  float b=bd2[tid];
  float msum=0.f;
  for (int r=0;r<N1;r++){
    float t2v=t2_st[(size_t)(k*N1+r)*Dn+tid];
    float z = sdinv[r]*(acc[r*Dn+tid]+t2v*sdinv[r]) + b;
    z_st[(size_t)k*N1*Dn + (size_t)r*Dn + tid]=z;
    msum+=z;
  }
  h_mean[k*Dn+tid]=msum*(1.0f/49.0f);
}

// ---------------- per-step logp contributions ----------------

__global__ __launch_bounds__(256) void k_c(const int* __restrict__ rec, const float* __restrict__ m_arr,
    const float* __restrict__ e_arr, const int* __restrict__ lab_idx, const float* __restrict__ lab_means,
    const float* __restrict__ z_st, const float* __restrict__ h_mean, const float* __restrict__ z_pocket,
    const float* __restrict__ zl_mean, const float* __restrict__ Wg, const float* __restrict__ Wh,
    const float* __restrict__ bh, float* __restrict__ out){
  const int t = blockIdx.x;
  if (!rec[3*Tn+t]) return;
  const int u=rec[t], v=rec[Tn+t], bidx=rec[2*Tn+t], doe=rec[4*Tn+t], sidx=rec[5*Tn+t];
  const float timef=(float)sidx;
  __shared__ float g[N1];
  __shared__ float4 red[256];
  const int tid=threadIdx.x, lane=tid&63, wv=tid>>6;
  const float* zs = z_st + (size_t)sidx*N1*Dn;
  for (int r=wv; r<N1; r+=4){
    const float4 z4=*(const float4*)(zs + (size_t)r*Dn + lane*4);
    const float4 g4=*(const float4*)(Wg + 524 + lane*4);
    float p = z4.x*g4.x+z4.y*g4.y+z4.z*g4.z+z4.w*g4.w;
    for (int off=32; off>0; off>>=1) p += __shfl_down(p, off);
    if (lane==0) g[r] = p + Wg[780+lab_idx[r]] + m_arr[t*N1+r];
  }
  __syncthreads();
  float4 a=make_float4(0.f,0.f,0.f,0.f);
  if (doe){
    const int lu=lab_idx[u], lv=lab_idx[v];
    for (int rr=tid; rr<PHIn; rr+=256){
      float pv;
      if (rr==0) pv=timef;
      else if (rr<257)  pv=z_pocket[rr-1];
      else if (rr<513)  pv=zs[(size_t)u*Dn + (rr-257)];
      else if (rr<524)  pv=(lu==(rr-513))?1.f:0.f;
      else if (rr<780)  pv=zs[(size_t)v*Dn + (rr-524)];
      else if (rr<791)  pv=(lv==(rr-780))?1.f:0.f;
      else if (rr<1047) pv=h_mean[sidx*Dn + (rr-791)];
      else if (rr<1058) pv=lab_means[rr-1047];
      else if (rr<1314) pv=zl_mean[rr-1058];
      else              pv=lab_means[NAn + (rr-1314)];
      const float4 wr=*(const float4*)(Wh + rr*4);
      a.x=fmaf(pv,wr.x,a.x); a.y=fmaf(pv,wr.y,a.y); a.z=fmaf(pv,wr.z,a.z); a.w=fmaf(pv,wr.w,a.w);
    }
  }
  red[tid]=a;
  float gM=-INFINITY, gS=0.f;
  if (wv==0){
    float x=(lane<N1)? g[lane] : -INFINITY;
    gM=x;
    for (int off=32; off>0; off>>=1) gM=fmaxf(gM,__shfl_xor(gM,off));
    float ex=(lane<N1)? expf(x-gM):0.f;
    gS=ex;
    for (int off=32; off>0; off>>=1) gS+=__shfl_xor(gS,off);
  }
  for (int off=128; off>0; off>>=1){
    __syncthreads();
    if (tid<off){
      red[tid].x+=red[tid+off].x; red[tid].y+=red[tid+off].y;
      red[tid].z+=red[tid+off].z; red[tid].w+=red[tid+off].w;
    }
  }
  if (tid==0){
    float cg = g[v] - gM - logf(gS);
    float ch = 0.f;
    if (doe){
      float h0=red[0].x+bh[0]+e_arr[4*t+0];
      float h1=red[0].y+bh[1]+e_arr[4*t+1];
      float h2=red[0].z+bh[2]+e_arr[4*t+2];
      float h3=red[0].w+bh[3]+e_arr[4*t+3];
      float M=fmaxf(fmaxf(h0,h1),fmaxf(h2,h3));
      float se=expf(h0-M)+expf(h1-M)+expf(h2-M)+expf(h3-M);
      float hb=(bidx==0)?h0:(bidx==1)?h1:(bidx==2)?h2:h3;
      ch = hb - M - logf(se);
    }
    atomicAdd(out, cg+ch);
  }
}

// ---------------- launch ----------------

extern "C" void kernel_launch(void* const* d_in, const int* in_sizes, int n_in,
                              void* d_out, int out_size, void* d_ws, size_t ws_size,
                              hipStream_t stream){
  const float* x_p      =(const float*)d_in[0];
  const int*   src_p    =(const int*)d_in[1];
  const int*   dst_p    =(const int*)d_in[2];
  const float* x_l_geom =(const float*)d_in[3];
  const int*   x_l_label=(const int*)d_in[4];
  const int*   src_l    =(const int*)d_in[5];
  const int*   dst_l    =(const int*)d_in[6];
  const int*   bfs_index=(const int*)d_in[7];
  const int*   bfs_bond =(const int*)d_in[8];
  const float* Wp1=(const float*)d_in[9];
  const float* bp1=(const float*)d_in[10];
  const float* Wp2=(const float*)d_in[11];
  const float* bp2=(const float*)d_in[12];
  const float* Wl1=(const float*)d_in[13];
  const float* bl1=(const float*)d_in[14];
  const float* Wl2=(const float*)d_in[15];
  const float* bl2=(const float*)d_in[16];
  const float* Wd1=(const float*)d_in[17];
  const float* bd1=(const float*)d_in[18];
  const float* Wd2=(const float*)d_in[19];
  const float* bd2=(const float*)d_in[20];
  const float* Wg =(const float*)d_in[23];
  const float* Wh =(const float*)d_in[25];
  const float* bh =(const float*)d_in[26];

  char* w=(char*)d_ws;
  size_t off=0;
  auto alloc=[&](size_t bytes)->char*{ char* p=w+off; off=(off+bytes+255)&~((size_t)255); return p; };
  int*   deg    =(int*)alloc((size_t)NPn*4);
  float* dinvp  =(float*)alloc((size_t)NPn*4);
  float* odegw  =(float*)alloc((size_t)NPn*4);
  float* xagg   =(float*)alloc((size_t)NPn*16*4);
  float* zr     =(float*)alloc(Dn*4);
  float* z_pocket=(float*)alloc(Dn*4);
  float* zl_mean=(float*)alloc(Dn*4);
  float* h1_st  =(float*)alloc((size_t)NSTATES*N1*Dn*4);
  float* t2_st  =(float*)alloc((size_t)NSTATES*N1*Dn*4);
  float* z_st   =(float*)alloc((size_t)NSTATES*N1*Dn*4);
  float* h_mean =(float*)alloc((size_t)NSTATES*Dn*4);
  float* dinv_st=(float*)alloc((size_t)NSTATES*N1*4);
  float* m_arr  =(float*)alloc((size_t)Tn*N1*4);
  float* e_arr  =(float*)alloc((size_t)Tn*4*4);
  int*   rec    =(int*)alloc((size_t)6*Tn*4);
  int*   dirs   =(int*)alloc(194*4);
  int*   dird   =(int*)alloc(194*4);
  int*   lab_idx=(int*)alloc(N1*4);
  float* lab_means=(float*)alloc(2*NAn*4);
  int*   Sval   =(int*)alloc(4);
  (void)in_sizes;(void)n_in;(void)ws_size;

  hipMemsetAsync(deg,0,(size_t)NPn*4,stream);
  hipMemsetAsync(odegw,0,(size_t)NPn*4,stream);
  hipMemsetAsync(xagg,0,(size_t)NPn*16*4,stream);
  hipMemsetAsync(zr,0,Dn*4,stream);
  hipMemsetAsync(d_out,0,(size_t)out_size*sizeof(float),stream);

  // pocket GCN (collapsed to scatter + fused matvec + GEMV)
  k_deg<<<EPn/256,256,0,stream>>>(dst_p,deg);
  k_dinv<<<(NPn+255)/256,256,0,stream>>>(deg,dinvp);
  k_odegw<<<EPn/256,256,0,stream>>>(src_p,dst_p,dinvp,odegw);
  k_xagg<<<EPn*16/256,256,0,stream>>>(src_p,dst_p,x_p,dinvp,xagg);
  k_fuse<<<(NPn+CHN-1)/CHN,256,0,stream>>>(x_p,xagg,dinvp,odegw,Wp1,bp1,zr);
  k_zfin<<<1,256,0,stream>>>(zr,Wp2,bp2,z_pocket);
  // ligand GCN (H_init)
  k_lig<<<1,1024,0,stream>>>(x_l_geom,x_l_label,src_l,dst_l,Wl1,bl1,Wl2,bl2,zl_mean);
  // sequential control sim
  k_sim<<<1,64,0,stream>>>(x_l_label,bfs_index,bfs_bond,lab_idx,lab_means,dirs,dird,m_arr,e_arr,rec,Sval);
  // decoder GCN states
  k_d1<<<NSTATES,256,0,stream>>>(Sval,dirs,dird,lab_idx,Wd1,bd1,h1_st,dinv_st);
  k_d2a<<<NSTATES,1024,0,stream>>>(Sval,Wd2,h1_st,t2_st);
  k_d2b<<<NSTATES,256,0,stream>>>(Sval,dirs,dird,bd2,t2_st,dinv_st,z_st,h_mean);
  // logp
  k_c<<<Tn,256,0,stream>>>(rec,m_arr,e_arr,lab_idx,lab_means,z_st,h_mean,z_pocket,zl_mean,Wg,Wh,bh,(float*)d_out);
}

// Round 3
// 319.974 us; speedup vs baseline: 2.4126x; 1.4333x over previous
//
#include <hip/hip_runtime.h>
#include <math.h>

#define NPn 30000
#define EPn 480000
#define NLl 48
#define ELl 144
#define Tn 96
#define NAn 11
#define Dn 256
#define N1 49
#define NEGf (-1000000000.0f)
#define NSTATES 97
#define CHN 125
#define PC 13            // P columns: [g | u(4) | v(4) | hmean(4)]
#define YN (N1*PC)       // 637

// ---------------- pocket GCN (collapsed) ----------------

__global__ void k_deg(const int* __restrict__ dst, int* __restrict__ deg){
  int e = blockIdx.x*blockDim.x + threadIdx.x;
  if (e < EPn) atomicAdd(&deg[dst[e]], 1);
}

// lanes c<15: xagg[dst][c] += x_p[src][c]*dinv[src];  lane c==15: odegw[src] += dinv[dst]
__global__ void k_xagg(const int* __restrict__ src, const int* __restrict__ dst,
                       const float* __restrict__ xp, const int* __restrict__ deg,
                       float* __restrict__ xagg, float* __restrict__ odegw){
  int g = blockIdx.x*blockDim.x + threadIdx.x;
  int e = g>>4, c = g&15;
  if (e >= EPn) return;
  int s = src[e], d = dst[e];
  if (c < 15){
    float dvs = rsqrtf((float)(deg[s]+1));
    atomicAdd(&xagg[d*16+c], xp[s*15+c]*dvs);
  } else {
    float dvd = rsqrtf((float)(deg[d]+1));
    atomicAdd(&odegw[s], dvd);
  }
}

// fused: h1[n] = relu(dinv_n*((xagg[n]+x'[n]*dinv_n)) @ Wp1 + bp1); zr += coef_n*h1[n]
__global__ __launch_bounds__(256) void k_fuse(const float* __restrict__ xp, const float* __restrict__ xagg,
    const int* __restrict__ deg, const float* __restrict__ odegw,
    const float* __restrict__ Wp1, const float* __restrict__ bp1, float* __restrict__ zr){
  __shared__ float sx[CHN][16];
  __shared__ float sc[CHN];
  int tid = threadIdx.x;
  int base = blockIdx.x*CHN;
  float wcol[15];
  for (int k=0;k<15;k++) wcol[k]=Wp1[k*Dn+tid];
  float b = bp1[tid];
  for (int i=tid;i<CHN*16;i+=256){
    int n = base+(i>>4), c = i&15;
    float v = 0.f;
    if (n<NPn && c<15){
      float dv = rsqrtf((float)(deg[n]+1));
      v = (xagg[n*16+c] + xp[n*15+c]*dv)*dv;
    }
    sx[i>>4][i&15]=v;
  }
  for (int i=tid;i<CHN;i+=256){
    int n = base+i;
    float dv = (n<NPn)? rsqrtf((float)(deg[n]+1)) : 0.f;
    sc[i] = (n<NPn)? dv*(odegw[n]+dv) : 0.f;
  }
  __syncthreads();
  float acc = 0.f;
  int lim = (NPn-base < CHN)? (NPn-base) : CHN;
  for (int i=0;i<lim;i++){
    float d0 = b;
    for (int k=0;k<15;k++) d0 = fmaf(sx[i][k], wcol[k], d0);
    acc = fmaf(sc[i], fmaxf(d0,0.f), acc);
  }
  atomicAdd(&zr[tid], acc);
}

__global__ void k_zfin(const float* __restrict__ zr, const float* __restrict__ Wp2,
                       const float* __restrict__ bp2, float* __restrict__ z_pocket){
  __shared__ float sr[Dn];
  int tid=threadIdx.x;
  sr[tid]=zr[tid]*(1.0f/30000.0f);
  __syncthreads();
  float a=0.f;
  for (int k=0;k<Dn;k++) a=fmaf(sr[k],Wp2[(size_t)k*Dn+tid],a);
  z_pocket[tid]=a+bp2[tid];
}

// ---------------- ligand GCN mean (collapsed to weighted rowsum + GEMV) ----------------

__global__ __launch_bounds__(256) void k_lig(const float* __restrict__ xg, const int* __restrict__ lab,
    const int* __restrict__ srcl, const int* __restrict__ dstl,
    const float* __restrict__ Wl1, const float* __restrict__ bl1,
    const float* __restrict__ Wl2, const float* __restrict__ bl2,
    float* __restrict__ zl_mean){
  __shared__ float sW[15*Dn];
  __shared__ float svec[NLl*4];
  __shared__ float scnt[NLl*11];
  __shared__ float ow[NLl];
  __shared__ float rs[Dn];
  __shared__ float sdinv[NLl];
  __shared__ int sdeg[NLl];
  __shared__ int ses[ELl], sed[ELl];
  __shared__ int slab[NLl];
  int tid=threadIdx.x;
  if (tid<NLl){ sdeg[tid]=1; slab[tid]=lab[tid]; }
  for (int i=tid;i<NLl*4;i+=256) svec[i]=0.f;
  for (int i=tid;i<NLl*11;i+=256) scnt[i]=0.f;
  for (int i=tid;i<15*Dn;i+=256) sW[i]=Wl1[i];
  __syncthreads();
  if (tid<ELl){ ses[tid]=srcl[tid]; sed[tid]=dstl[tid]; atomicAdd(&sdeg[dstl[tid]],1); }
  __syncthreads();
  if (tid<NLl) sdinv[tid]=rsqrtf((float)sdeg[tid]);
  __syncthreads();
  if (tid<NLl){
    float dv=sdinv[tid];
    ow[tid]=dv;                              // self term of out-weight
    for (int q=0;q<4;q++) svec[tid*4+q]=xg[tid*4+q]*dv;
    scnt[tid*11+slab[tid]]=dv;               // self loop
  }
  __syncthreads();
  if (tid<ELl){
    int s=ses[tid], d=sed[tid];
    float dvs=sdinv[s];
    for (int q=0;q<4;q++) atomicAdd(&svec[d*4+q], xg[s*4+q]*dvs);
    atomicAdd(&scnt[d*11+slab[s]], dvs);
    atomicAdd(&ow[s], sdinv[d]);
  }
  __syncthreads();
  {
    int c=tid;
    float b=bl1[c];
    float rsum=0.f;
    for (int d=0;d<NLl;d++){
      float a=0.f;
      for (int q=0;q<4;q++)  a=fmaf(svec[d*4+q], sW[q*Dn+c], a);
      for (int aa=0;aa<11;aa++) a=fmaf(scnt[d*11+aa], sW[(4+aa)*Dn+c], a);
      float h=fmaxf(sdinv[d]*a + b, 0.f);
      rsum = fmaf(sdinv[d]*ow[d], h, rsum);
    }
    rs[c]=rsum*(1.0f/48.0f);
  }
  __syncthreads();
  {
    int c=tid;
    float a=0.f;
    for (int k=0;k<Dn;k++) a=fmaf(rs[k], Wl2[(size_t)k*Dn+c], a);
    zl_mean[c]=a+bl2[c];
  }
}

// ---------------- P = Wd2 @ [wg2 | Whu | Whv | Whh]  (256 blocks x 64) ----------------

__global__ __launch_bounds__(64) void k_pre(const float* __restrict__ Wd2, const float* __restrict__ Wg,
    const float* __restrict__ Wh, float* __restrict__ Pm){
  int k = blockIdx.x;
  int lane = threadIdx.x;
  float pg=0.f;
  float4 pu=make_float4(0,0,0,0), pv=make_float4(0,0,0,0), ph=make_float4(0,0,0,0);
  for (int q=0;q<4;q++){
    int n = lane + 64*q;
    float w = Wd2[(size_t)k*Dn+n];
    pg = fmaf(w, Wg[524+n], pg);
    float4 a=*(const float4*)&Wh[(size_t)(257+n)*4];
    float4 b=*(const float4*)&Wh[(size_t)(524+n)*4];
    float4 c=*(const float4*)&Wh[(size_t)(791+n)*4];
    pu.x=fmaf(w,a.x,pu.x); pu.y=fmaf(w,a.y,pu.y); pu.z=fmaf(w,a.z,pu.z); pu.w=fmaf(w,a.w,pu.w);
    pv.x=fmaf(w,b.x,pv.x); pv.y=fmaf(w,b.y,pv.y); pv.z=fmaf(w,b.z,pv.z); pv.w=fmaf(w,b.w,pv.w);
    ph.x=fmaf(w,c.x,ph.x); ph.y=fmaf(w,c.y,ph.y); ph.z=fmaf(w,c.z,ph.z); ph.w=fmaf(w,c.w,ph.w);
  }
  for (int off=32; off>0; off>>=1){
    pg += __shfl_xor(pg,off);
    pu.x+=__shfl_xor(pu.x,off); pu.y+=__shfl_xor(pu.y,off); pu.z+=__shfl_xor(pu.z,off); pu.w+=__shfl_xor(pu.w,off);
    pv.x+=__shfl_xor(pv.x,off); pv.y+=__shfl_xor(pv.y,off); pv.z+=__shfl_xor(pv.z,off); pv.w+=__shfl_xor(pv.w,off);
    ph.x+=__shfl_xor(ph.x,off); ph.y+=__shfl_xor(ph.y,off); ph.z+=__shfl_xor(ph.z,off); ph.w+=__shfl_xor(ph.w,off);
  }
  if (lane==0){
    float* o = Pm + k*PC;
    o[0]=pg; o[1]=pu.x; o[2]=pu.y; o[3]=pu.z; o[4]=pu.w;
    o[5]=pv.x; o[6]=pv.y; o[7]=pv.z; o[8]=pv.w;
    o[9]=ph.x; o[10]=ph.y; o[11]=ph.z; o[12]=ph.w;
  }
}

// ---------------- hconst4: all row-constant hlog terms ----------------

__global__ __launch_bounds__(64) void k_hc(const float* __restrict__ zp, const float* __restrict__ zl,
    const float* __restrict__ lm, const float* __restrict__ b2, const float* __restrict__ Wh,
    const float* __restrict__ bh, float* __restrict__ hc4){
  int lane=threadIdx.x;
  float4 h=make_float4(0,0,0,0);
  for (int q=0;q<4;q++){
    int n=lane+64*q;
    float4 w1=*(const float4*)&Wh[(size_t)(1+n)*4];
    float4 w2=*(const float4*)&Wh[(size_t)(1058+n)*4];
    float4 wu=*(const float4*)&Wh[(size_t)(257+n)*4];
    float4 wv=*(const float4*)&Wh[(size_t)(524+n)*4];
    float4 wh=*(const float4*)&Wh[(size_t)(791+n)*4];
    float zpn=zp[n], zln=zl[n], bn=b2[n];
    h.x += zpn*w1.x + zln*w2.x + bn*(wu.x+wv.x+wh.x);
    h.y += zpn*w1.y + zln*w2.y + bn*(wu.y+wv.y+wh.y);
    h.z += zpn*w1.z + zln*w2.z + bn*(wu.z+wv.z+wh.z);
    h.w += zpn*w1.w + zln*w2.w + bn*(wu.w+wv.w+wh.w);
  }
  if (lane<NAn){
    float4 wa=*(const float4*)&Wh[(size_t)(1047+lane)*4];
    float4 wb=*(const float4*)&Wh[(size_t)(1314+lane)*4];
    float a=lm[lane], bb=lm[NAn+lane];
    h.x += a*wa.x + bb*wb.x; h.y += a*wa.y + bb*wb.y;
    h.z += a*wa.z + bb*wb.z; h.w += a*wa.w + bb*wb.w;
  }
  for (int off=32; off>0; off>>=1){
    h.x+=__shfl_xor(h.x,off); h.y+=__shfl_xor(h.y,off);
    h.z+=__shfl_xor(h.z,off); h.w+=__shfl_xor(h.w,off);
  }
  if (lane==0){
    hc4[0]=h.x+bh[0]; hc4[1]=h.y+bh[1]; hc4[2]=h.z+bh[2]; hc4[3]=h.w+bh[3];
  }
}

// ---------------- sequential control simulation (1 wave) ----------------

__global__ __launch_bounds__(64) void k_sim(const int* __restrict__ lab_in, const int* __restrict__ bfs_i,
    const int* __restrict__ bfs_b, int* __restrict__ lab_idx, float* __restrict__ lab_means,
    int* __restrict__ dirs, int* __restrict__ dird, float* __restrict__ m_arr, float* __restrict__ e_arr,
    int* __restrict__ rec, int* __restrict__ Sout){
  __shared__ float val[N1];
  __shared__ int closed[N1];
  __shared__ unsigned char adj[N1*N1];
  __shared__ int Q[Tn+1];
  __shared__ float mnou_sh[N1];
  int lane = threadIdx.x;
  if (lane < N1){
    int l = (lane<NLl)? lab_in[lane] : (NAn-1);
    lab_idx[lane]=l;
    float vv;
    switch(l){
      case 0: vv=4.f; break; case 1: vv=1.f; break; case 2: vv=3.f; break; case 3: vv=1.f; break;
      case 4: vv=2.f; break; case 5: vv=1.f; break; case 6: vv=5.f; break; case 7: vv=1.f; break;
      case 8: vv=6.f; break; case 9: vv=1.f; break; default: vv=1000.f; break;
    }
    val[lane]=vv; closed[lane]=0;
  }
  for (int i=lane;i<N1*N1;i+=64) adj[i]=0;
  for (int i=lane;i<=Tn;i+=64) Q[i]=0;
  if (lane < NAn){
    int cnt=0;
    for (int i=0;i<NLl;i++) cnt += (lab_in[i]==lane)?1:0;
    lab_means[lane] = ((float)cnt + ((lane==NAn-1)?1.f:0.f))*(1.0f/49.0f);
    lab_means[NAn+lane] = (float)cnt*(1.0f/48.0f);
  }
  __syncthreads();
  if (lane==0){ Q[0]=bfs_i[0]; dirs[192]=bfs_i[0]; dird[192]=bfs_i[1]; }
  __syncthreads();
  int head=0, tail=1, ec=0, timec=0;
  for (int t=0;t<Tn;t++){
    int v = bfs_i[2*t+1];
    int bix = bfs_b[t];
    int active = (tail>head)?1:0;
    int u = Q[(head<=Tn)?head:Tn];
    float valu = val[u], valv = val[v];
    if (lane<N1){
      float base = ((val[lane]<1.0f) || (closed[lane]!=0) || (adj[u*N1+lane]!=0)) ? NEGf : 0.0f;
      if (lane==u) base=NEGf;
      float mnou = (valu<1.0f)? NEGf : base;
      float m = mnou;
      if (lane==v) m=0.0f;
      if (lane==NLl) m=0.0f;
      m_arr[t*N1+lane]=m;
      mnou_sh[lane]=mnou;
    }
    __syncthreads();
    if (lane<4){
      float mnv = mnou_sh[v];
      float mv = fminf(valu, valv);
      float e;
      if (mv<=0.f) e=NEGf;
      else if (mv<=1.f) e=((lane==1)||(lane==2))?NEGf:0.f;
      else if (mv<=2.f) e=(lane==2)?NEGf:0.f;
      else e=0.f;
      if (mnv <= NEGf*0.5f) e=NEGf;
      if (lane==bix) e=0.f;
      e_arr[t*4+lane]=e;
    }
    int is_stop = (v==NLl)?1:0;
    int pop = active & is_stop;
    int doe = active & (is_stop^1);
    if (lane==0){
      rec[t]=u; rec[Tn+t]=v; rec[2*Tn+t]=bix; rec[3*Tn+t]=active; rec[4*Tn+t]=doe; rec[5*Tn+t]=timec;
    }
    __syncthreads();
    if (lane==0 && doe){
      if (tail<=Tn) Q[tail]=v;
      if (ec<192){ dirs[ec]=u; dird[ec]=v; dirs[ec+1]=v; dird[ec+1]=u; }
      float dec = (bix==0)?1.f:(bix==1)?2.f:(bix==2)?3.f:1.5f;
      val[u]-=dec; val[v]-=dec;
      adj[u*N1+v]=1; adj[v*N1+u]=1;
    }
    if (lane==0 && pop) closed[u]=1;
    head+=pop; tail+=doe; ec+=2*doe; timec+=doe;
    __syncthreads();
  }
  if (lane==0) Sout[0]=ec/2;
}

// ---------------- decoder states: Zc[k] = S_k * (h1_k @ P)  (49x13 per state) ----------------

__global__ __launch_bounds__(256) void k_dec(const int* __restrict__ Sp, const int* __restrict__ dirs,
    const int* __restrict__ dird, const int* __restrict__ lab_idx,
    const float* __restrict__ Wd1, const float* __restrict__ bd1,
    const float* __restrict__ Pm, float* __restrict__ Zc){
  int k = blockIdx.x;
  if (k > Sp[0]) return;
  __shared__ float sW[11*Dn];
  __shared__ float sP[Dn*PC];
  __shared__ float hT[Dn*N1];      // transposed h1: hT[c*49+r]
  __shared__ float cnt[N1*11];
  __shared__ float y1[YN];
  __shared__ float za[YN];
  __shared__ float sdinv[N1];
  __shared__ int sdeg[N1];
  __shared__ int se[192], sd[192];
  __shared__ int slab[N1];
  int tid=threadIdx.x;
  int ecnt = (k==0)?1:(2*k);
  int base = (k==0)?192:0;
  if (tid<N1){ sdeg[tid]=1; slab[tid]=lab_idx[tid]; }
  for (int i=tid;i<N1*11;i+=256) cnt[i]=0.f;
  for (int i=tid;i<11*Dn;i+=256) sW[i]=Wd1[i];
  for (int i=tid;i<Dn*PC;i+=256) sP[i]=Pm[i];
  __syncthreads();
  if (tid<ecnt){ se[tid]=dirs[base+tid]; sd[tid]=dird[base+tid]; atomicAdd(&sdeg[sd[tid]],1); }
  __syncthreads();
  if (tid<N1) sdinv[tid]=rsqrtf((float)sdeg[tid]);
  __syncthreads();
  if (tid<N1) cnt[tid*11+slab[tid]] = sdinv[tid];     // self loop
  __syncthreads();
  if (tid<ecnt) atomicAdd(&cnt[sd[tid]*11+slab[se[tid]]], sdinv[se[tid]]);
  __syncthreads();
  { // h1 transposed
    int c=tid;
    float b=bd1[c];
    for (int r=0;r<N1;r++){
      float s=0.f;
      for (int a=0;a<11;a++) s=fmaf(cnt[r*11+a], sW[a*Dn+c], s);
      hT[c*N1+r]=fmaxf(sdinv[r]*s + b, 0.f);
    }
  }
  __syncthreads();
  for (int idx=tid; idx<YN; idx+=256){
    int r=idx/PC, j=idx-r*PC;
    float acc=0.f;
    for (int c=0;c<Dn;c++) acc=fmaf(hT[c*N1+r], sP[c*PC+j], acc);
    y1[idx]=acc;
    za[idx]=sdinv[r]*acc;        // self term (outer dinv applied at end)
  }
  __syncthreads();
  for (int i=tid; i<ecnt*PC; i+=256){
    int e=i/PC, j=i-e*PC;
    atomicAdd(&za[sd[e]*PC+j], sdinv[se[e]]*y1[se[e]*PC+j]);
  }
  __syncthreads();
  for (int idx=tid; idx<YN; idx+=256){
    int r=idx/PC;
    Zc[(size_t)k*YN+idx]=sdinv[r]*za[idx];
  }
}

// ---------------- per-step logp (1 wave per step) ----------------

__global__ __launch_bounds__(64) void k_c(const int* __restrict__ rec, const float* __restrict__ m_arr,
    const float* __restrict__ e_arr, const int* __restrict__ lab_idx, const float* __restrict__ Zc,
    const float* __restrict__ hc4, const float* __restrict__ Wg, const float* __restrict__ Wh,
    float* __restrict__ out){
  const int t = blockIdx.x;
  if (!rec[3*Tn+t]) return;
  const int u=rec[t], v=rec[Tn+t], bidx=rec[2*Tn+t], doe=rec[4*Tn+t], sidx=rec[5*Tn+t];
  const int lane=threadIdx.x;
  const float* Z = Zc + (size_t)sidx*YN;
  float g = -INFINITY;
  float4 hm = make_float4(0,0,0,0);
  if (lane<N1){
    const float* zr = Z + lane*PC;
    g = zr[0] + Wg[780+lab_idx[lane]] + m_arr[t*N1+lane];
    hm.x=zr[9]; hm.y=zr[10]; hm.z=zr[11]; hm.w=zr[12];
  }
  float gv = __shfl(g, v);
  float gM = g;
  for (int off=32; off>0; off>>=1) gM = fmaxf(gM, __shfl_xor(gM, off));
  float ex = (lane<N1)? expf(g-gM) : 0.f;
  float gS = ex;
  for (int off=32; off>0; off>>=1){
    gS += __shfl_xor(gS, off);
    hm.x+=__shfl_xor(hm.x,off); hm.y+=__shfl_xor(hm.y,off);
    hm.z+=__shfl_xor(hm.z,off); hm.w+=__shfl_xor(hm.w,off);
  }
  if (lane==0){
    float res = gv - gM - logf(gS);
    if (doe){
      const int lu=lab_idx[u], lv=lab_idx[v];
      const float tf=(float)sidx;
      float h[4];
      for (int j=0;j<4;j++){
        float hmj = (j==0)?hm.x:(j==1)?hm.y:(j==2)?hm.z:hm.w;
        h[j] = hc4[j] + tf*Wh[j] + Wh[(513+lu)*4+j] + Wh[(780+lv)*4+j]
             + Z[u*PC+1+j] + Z[v*PC+5+j] + hmj*(1.0f/49.0f) + e_arr[4*t+j];
      }
      float M=fmaxf(fmaxf(h[0],h[1]),fmaxf(h[2],h[3]));
      float se=expf(h[0]-M)+expf(h[1]-M)+expf(h[2]-M)+expf(h[3]-M);
      float hb=(bidx==0)?h[0]:(bidx==1)?h[1]:(bidx==2)?h[2]:h[3];
      res += hb - M - logf(se);
    }
    atomicAdd(out, res);
  }
}

// ---------------- launch ----------------

extern "C" void kernel_launch(void* const* d_in, const int* in_sizes, int n_in,
                              void* d_out, int out_size, void* d_ws, size_t ws_size,
                              hipStream_t stream){
  const float* x_p      =(const float*)d_in[0];
  const int*   src_p    =(const int*)d_in[1];
  const int*   dst_p    =(const int*)d_in[2];
  const float* x_l_geom =(const float*)d_in[3];
  const int*   x_l_label=(const int*)d_in[4];
  const int*   src_l    =(const int*)d_in[5];
  const int*   dst_l    =(const int*)d_in[6];
  const int*   bfs_index=(const int*)d_in[7];
  const int*   bfs_bond =(const int*)d_in[8];
  const float* Wp1=(const float*)d_in[9];
  const float* bp1=(const float*)d_in[10];
  const float* Wp2=(const float*)d_in[11];
  const float* bp2=(const float*)d_in[12];
  const float* Wl1=(const float*)d_in[13];
  const float* bl1=(const float*)d_in[14];
  const float* Wl2=(const float*)d_in[15];
  const float* bl2=(const float*)d_in[16];
  const float* Wd1=(const float*)d_in[17];
  const float* bd1=(const float*)d_in[18];
  const float* Wd2=(const float*)d_in[19];
  const float* bd2=(const float*)d_in[20];
  const float* Wg =(const float*)d_in[23];
  const float* Wh =(const float*)d_in[25];
  const float* bh =(const float*)d_in[26];

  char* w=(char*)d_ws;
  size_t off=0;
  auto alloc=[&](size_t bytes)->char*{ char* p=w+off; off=(off+bytes+255)&~((size_t)255); return p; };
  // ---- contiguous zero-init region ----
  int*   deg    =(int*)alloc((size_t)NPn*4);
  float* odegw  =(float*)alloc((size_t)NPn*4);
  float* xagg   =(float*)alloc((size_t)NPn*16*4);
  float* zr     =(float*)alloc(Dn*4);
  size_t zero_span = off;
  // ---- rest ----
  float* z_pocket=(float*)alloc(Dn*4);
  float* zl_mean=(float*)alloc(Dn*4);
  float* Pm     =(float*)alloc(Dn*PC*4);
  float* hc4    =(float*)alloc(4*4);
  float* Zc     =(float*)alloc((size_t)NSTATES*YN*4);
  float* m_arr  =(float*)alloc((size_t)Tn*N1*4);
  float* e_arr  =(float*)alloc((size_t)Tn*4*4);
  int*   rec    =(int*)alloc((size_t)6*Tn*4);
  int*   dirs   =(int*)alloc(194*4);
  int*   dird   =(int*)alloc(194*4);
  int*   lab_idx=(int*)alloc(N1*4);
  float* lab_means=(float*)alloc(2*NAn*4);
  int*   Sval   =(int*)alloc(4);
  (void)in_sizes;(void)n_in;(void)ws_size;

  hipMemsetAsync(d_ws, 0, zero_span, stream);
  hipMemsetAsync(d_out, 0, (size_t)out_size*sizeof(float), stream);

  // precompute P (independent of data path)
  k_pre<<<Dn,64,0,stream>>>(Wd2,Wg,Wh,Pm);
  // pocket GCN
  k_deg<<<EPn/256,256,0,stream>>>(dst_p,deg);
  k_xagg<<<EPn*16/256,256,0,stream>>>(src_p,dst_p,x_p,deg,xagg,odegw);
  k_fuse<<<(NPn+CHN-1)/CHN,256,0,stream>>>(x_p,xagg,deg,odegw,Wp1,bp1,zr);
  k_zfin<<<1,256,0,stream>>>(zr,Wp2,bp2,z_pocket);
  // ligand GCN mean
  k_lig<<<1,256,0,stream>>>(x_l_geom,x_l_label,src_l,dst_l,Wl1,bl1,Wl2,bl2,zl_mean);
  // control sim
  k_sim<<<1,64,0,stream>>>(x_l_label,bfs_index,bfs_bond,lab_idx,lab_means,dirs,dird,m_arr,e_arr,rec,Sval);
  // hconst (needs z_pocket, zl_mean, lab_means, bd2)
  k_hc<<<1,64,0,stream>>>(z_pocket,zl_mean,lab_means,bd2,Wh,bh,hc4);
  // decoder states (tiny contraction)
  k_dec<<<NSTATES,256,0,stream>>>(Sval,dirs,dird,lab_idx,Wd1,bd1,Pm,Zc);
  // per-step logp
  k_c<<<Tn,64,0,stream>>>(rec,m_arr,e_arr,lab_idx,Zc,hc4,Wg,Wh,(float*)d_out);
}

// Round 5
// 285.703 us; speedup vs baseline: 2.7019x; 1.1200x over previous
//
#include <hip/hip_runtime.h>
#include <math.h>

#define NPn 30000
#define EPn 480000
#define NLl 48
#define ELl 144
#define Tn 96
#define NAn 11
#define Dn 256
#define N1 49
#define NEGf (-1000000000.0f)
#define NSTATES 97
#define CHN 125
#define PC 13            // P columns: [g | u(4) | v(4) | hmean(4)]
#define YN (N1*PC)       // 637

// ================= kernel A: deg atomics | sim (1 wave) | lig | pre =================

__global__ __launch_bounds__(256) void kA(
    // deg part
    const int* __restrict__ dst_p, int* __restrict__ deg,
    // sim part
    const int* __restrict__ lab_in, const int* __restrict__ bfs_i, const int* __restrict__ bfs_b,
    int* __restrict__ lab_idx, float* __restrict__ lab_means,
    int* __restrict__ dirs, int* __restrict__ dird, float* __restrict__ m_arr,
    float* __restrict__ e_arr, int* __restrict__ rec, int* __restrict__ Sout,
    // lig part
    const float* __restrict__ xg, const int* __restrict__ srcl, const int* __restrict__ dstl,
    const float* __restrict__ Wl1, const float* __restrict__ bl1,
    const float* __restrict__ Wl2, const float* __restrict__ bl2, float* __restrict__ zl_mean,
    // pre part
    const float* __restrict__ Wd2, const float* __restrict__ Wg, const float* __restrict__ Wh,
    float* __restrict__ Pm){
  const int bid = blockIdx.x;
  const int tid = threadIdx.x;

  if (bid == 0){
    // ---------- register-resident control sim (wave 0 only) ----------
    if (tid >= 64) return;
    const int lane = tid;
    // preload bfs into registers
    int vA = bfs_i[2*lane+1];                       // t = lane (0..63)
    int vB = (lane<Tn-64)? bfs_i[2*(64+lane)+1] : 0;
    int bA = bfs_b[lane];
    int bB = (lane<Tn-64)? bfs_b[64+lane] : 0;
    // labels & valence
    int labv = (lane<NLl)? lab_in[lane] : (NAn-1);
    float val_r;
    switch(labv){
      case 0: val_r=4.f; break; case 1: val_r=1.f; break; case 2: val_r=3.f; break;
      case 3: val_r=1.f; break; case 4: val_r=2.f; break; case 5: val_r=1.f; break;
      case 6: val_r=5.f; break; case 7: val_r=1.f; break; case 8: val_r=6.f; break;
      case 9: val_r=1.f; break; default: val_r=1000.f; break;
    }
    if (lane<N1) lab_idx[lane]=labv;
    for (int a=0;a<NAn;a++){
      unsigned long long mask = __ballot(lane<NLl && labv==a);
      int cnt = __popcll(mask);
      if (lane==a){
        lab_means[a]     = ((float)cnt + ((a==NAn-1)?1.f:0.f))*(1.0f/49.0f);
        lab_means[NAn+a] = (float)cnt*(1.0f/48.0f);
      }
    }
    int closed_r = 0;
    unsigned long long adjmask = 0ull;
    int q0 = 0, q1 = 0;
    int e0s = bfs_i[0], e0d = bfs_i[1];
    if (lane==0){ q0 = e0s; dirs[192]=e0s; dird[192]=e0d; }
    int head=0, tail=1, ec=0, timec=0;
    for (int t=0;t<Tn;t++){
      int v   = (t<64)? __shfl(vA,t) : __shfl(vB,t-64);
      int bix = (t<64)? __shfl(bA,t) : __shfl(bB,t-64);
      int active = (tail>head)?1:0;
      int u = (head<64)? __shfl(q0,head) : __shfl(q1,head-64);
      float valu = __shfl(val_r,u);
      float valv = __shfl(val_r,v);
      float base = (val_r<1.f || closed_r || ((adjmask>>u)&1ull)) ? NEGf : 0.f;
      if (lane==u) base=NEGf;
      float mnou = (valu<1.f)? NEGf : base;
      float m = mnou;
      if (lane==v) m=0.f;
      if (lane==NLl) m=0.f;
      if (lane<N1) m_arr[t*N1+lane]=m;
      float mnv = __shfl(mnou,v);
      if (lane<4){
        float mv = fminf(valu,valv);
        float e;
        if (mv<=0.f) e=NEGf;
        else if (mv<=1.f) e=((lane==1)||(lane==2))?NEGf:0.f;
        else if (mv<=2.f) e=(lane==2)?NEGf:0.f;
        else e=0.f;
        if (mnv <= NEGf*0.5f) e=NEGf;
        if (lane==bix) e=0.f;
        e_arr[t*4+lane]=e;
      }
      int is_stop = (v==NLl)?1:0;
      int pop = active & is_stop;
      int doe = active & (is_stop^1);
      if (lane==0){
        rec[t]=u; rec[Tn+t]=v; rec[2*Tn+t]=bix; rec[3*Tn+t]=active; rec[4*Tn+t]=doe; rec[5*Tn+t]=timec;
      }
      if (doe){
        if (tail<64){ if (lane==tail) q0=v; }
        else        { if (lane==tail-64) q1=v; }
        if (lane==0){ dirs[ec]=u; dird[ec]=v; dirs[ec+1]=v; dird[ec+1]=u; }
        float dec = (bix==0)?1.f:(bix==1)?2.f:(bix==2)?3.f:1.5f;
        if (lane==u) val_r-=dec;
        if (lane==v) val_r-=dec;
        if (lane==u) adjmask |= (1ull<<v);
        if (lane==v) adjmask |= (1ull<<u);
      }
      if (pop && lane==u) closed_r=1;
      head+=pop; tail+=doe; ec+=2*doe; timec+=doe;
    }
    if (lane==0) Sout[0]=ec/2;
    return;
  }

  if (bid == 1){
    // ---------- ligand GCN mean (collapsed) ----------
    __shared__ float sW[15*Dn];
    __shared__ float svec[NLl*4];
    __shared__ float scnt[NLl*11];
    __shared__ float ow[NLl];
    __shared__ float rs[Dn];
    __shared__ float sdinv[NLl];
    __shared__ int sdeg[NLl];
    __shared__ int ses[ELl], sed[ELl];
    __shared__ int slab[NLl];
    if (tid<NLl){ sdeg[tid]=1; slab[tid]=lab_in[tid]; }
    for (int i=tid;i<NLl*4;i+=256) svec[i]=0.f;
    for (int i=tid;i<NLl*11;i+=256) scnt[i]=0.f;
    for (int i=tid;i<15*Dn;i+=256) sW[i]=Wl1[i];
    __syncthreads();
    if (tid<ELl){ ses[tid]=srcl[tid]; sed[tid]=dstl[tid]; atomicAdd(&sdeg[dstl[tid]],1); }
    __syncthreads();
    if (tid<NLl) sdinv[tid]=rsqrtf((float)sdeg[tid]);
    __syncthreads();
    if (tid<NLl){
      float dv=sdinv[tid];
      ow[tid]=dv;
      for (int q=0;q<4;q++) svec[tid*4+q]=xg[tid*4+q]*dv;
      scnt[tid*11+slab[tid]]=dv;
    }
    __syncthreads();
    if (tid<ELl){
      int s=ses[tid], d=sed[tid];
      float dvs=sdinv[s];
      for (int q=0;q<4;q++) atomicAdd(&svec[d*4+q], xg[s*4+q]*dvs);
      atomicAdd(&scnt[d*11+slab[s]], dvs);
      atomicAdd(&ow[s], sdinv[d]);
    }
    __syncthreads();
    {
      int c=tid;
      float b=bl1[c];
      float rsum=0.f;
      for (int d=0;d<NLl;d++){
        float a=0.f;
        for (int q=0;q<4;q++)  a=fmaf(svec[d*4+q], sW[q*Dn+c], a);
        for (int aa=0;aa<11;aa++) a=fmaf(scnt[d*11+aa], sW[(4+aa)*Dn+c], a);
        float h=fmaxf(sdinv[d]*a + b, 0.f);
        rsum = fmaf(sdinv[d]*ow[d], h, rsum);
      }
      rs[c]=rsum*(1.0f/48.0f);
    }
    __syncthreads();
    {
      int c=tid;
      float a=0.f;
      for (int k=0;k<Dn;k++) a=fmaf(rs[k], Wl2[(size_t)k*Dn+c], a);
      zl_mean[c]=a+bl2[c];
    }
    return;
  }

  if (bid < 2+64){
    // ---------- P = Wd2 @ [wg2 | Whu | Whv | Whh] : one k per wave ----------
    const int lane = tid&63, wv = tid>>6;
    const int k = (bid-2)*4 + wv;
    float pg=0.f;
    float4 pu=make_float4(0,0,0,0), pv=make_float4(0,0,0,0), ph=make_float4(0,0,0,0);
    for (int q=0;q<4;q++){
      int n = lane + 64*q;
      float w = Wd2[(size_t)k*Dn+n];
      pg = fmaf(w, Wg[524+n], pg);
      float4 a=*(const float4*)&Wh[(size_t)(257+n)*4];
      float4 b=*(const float4*)&Wh[(size_t)(524+n)*4];
      float4 c=*(const float4*)&Wh[(size_t)(791+n)*4];
      pu.x=fmaf(w,a.x,pu.x); pu.y=fmaf(w,a.y,pu.y); pu.z=fmaf(w,a.z,pu.z); pu.w=fmaf(w,a.w,pu.w);
      pv.x=fmaf(w,b.x,pv.x); pv.y=fmaf(w,b.y,pv.y); pv.z=fmaf(w,b.z,pv.z); pv.w=fmaf(w,b.w,pv.w);
      ph.x=fmaf(w,c.x,ph.x); ph.y=fmaf(w,c.y,ph.y); ph.z=fmaf(w,c.z,ph.z); ph.w=fmaf(w,c.w,ph.w);
    }
    for (int off=32; off>0; off>>=1){
      pg += __shfl_xor(pg,off);
      pu.x+=__shfl_xor(pu.x,off); pu.y+=__shfl_xor(pu.y,off); pu.z+=__shfl_xor(pu.z,off); pu.w+=__shfl_xor(pu.w,off);
      pv.x+=__shfl_xor(pv.x,off); pv.y+=__shfl_xor(pv.y,off); pv.z+=__shfl_xor(pv.z,off); pv.w+=__shfl_xor(pv.w,off);
      ph.x+=__shfl_xor(ph.x,off); ph.y+=__shfl_xor(ph.y,off); ph.z+=__shfl_xor(ph.z,off); ph.w+=__shfl_xor(ph.w,off);
    }
    if (lane==0){
      float* o = Pm + k*PC;
      o[0]=pg; o[1]=pu.x; o[2]=pu.y; o[3]=pu.z; o[4]=pu.w;
      o[5]=pv.x; o[6]=pv.y; o[7]=pv.z; o[8]=pv.w;
      o[9]=ph.x; o[10]=ph.y; o[11]=ph.z; o[12]=ph.w;
    }
    return;
  }

  // ---------- deg atomics ----------
  {
    int e = (bid-66)*256 + tid;
    if (e < EPn) atomicAdd(&deg[dst_p[e]], 1);
  }
}

// ================= pocket GCN (collapsed) =================

// lanes c<15: xagg[dst][c] += x_p[src][c]*dinv[src];  lane c==15: odegw[src] += dinv[dst]
__global__ void k_xagg(const int* __restrict__ src, const int* __restrict__ dst,
                       const float* __restrict__ xp, const int* __restrict__ deg,
                       float* __restrict__ xagg, float* __restrict__ odegw){
  int g = blockIdx.x*blockDim.x + threadIdx.x;
  int e = g>>4, c = g&15;
  if (e >= EPn) return;
  int s = src[e], d = dst[e];
  if (c < 15){
    float dvs = rsqrtf((float)(deg[s]+1));
    atomicAdd(&xagg[d*16+c], xp[s*15+c]*dvs);
  } else {
    float dvd = rsqrtf((float)(deg[d]+1));
    atomicAdd(&odegw[s], dvd);
  }
}

__global__ __launch_bounds__(256) void k_fuse(const float* __restrict__ xp, const float* __restrict__ xagg,
    const int* __restrict__ deg, const float* __restrict__ odegw,
    const float* __restrict__ Wp1, const float* __restrict__ bp1, float* __restrict__ zr){
  __shared__ float sx[CHN][16];
  __shared__ float sc[CHN];
  int tid = threadIdx.x;
  int base = blockIdx.x*CHN;
  float wcol[15];
  for (int k=0;k<15;k++) wcol[k]=Wp1[k*Dn+tid];
  float b = bp1[tid];
  for (int i=tid;i<CHN*16;i+=256){
    int n = base+(i>>4), c = i&15;
    float v = 0.f;
    if (n<NPn && c<15){
      float dv = rsqrtf((float)(deg[n]+1));
      v = (xagg[n*16+c] + xp[n*15+c]*dv)*dv;
    }
    sx[i>>4][i&15]=v;
  }
  for (int i=tid;i<CHN;i+=256){
    int n = base+i;
    float dv = (n<NPn)? rsqrtf((float)(deg[n]+1)) : 0.f;
    sc[i] = (n<NPn)? dv*(odegw[n]+dv) : 0.f;
  }
  __syncthreads();
  float acc = 0.f;
  int lim = (NPn-base < CHN)? (NPn-base) : CHN;
  for (int i=0;i<lim;i++){
    float d0 = b;
    for (int k=0;k<15;k++) d0 = fmaf(sx[i][k], wcol[k], d0);
    acc = fmaf(sc[i], fmaxf(d0,0.f), acc);
  }
  atomicAdd(&zr[tid], acc);
}

// ================= z_pocket GEMV + hconst (fused) =================

__global__ __launch_bounds__(256) void k_zh(const float* __restrict__ zr, const float* __restrict__ Wp2,
    const float* __restrict__ bp2, const float* __restrict__ zl, const float* __restrict__ lm,
    const float* __restrict__ b2, const float* __restrict__ Wh, const float* __restrict__ bh,
    float* __restrict__ hc4){
  __shared__ float sr[Dn];
  __shared__ float zp[Dn];
  int tid=threadIdx.x;
  sr[tid]=zr[tid]*(1.0f/30000.0f);
  __syncthreads();
  float a=0.f;
  for (int k=0;k<Dn;k++) a=fmaf(sr[k],Wp2[(size_t)k*Dn+tid],a);
  zp[tid]=a+bp2[tid];
  __syncthreads();
  if (tid<64){
    int lane=tid;
    float4 h=make_float4(0,0,0,0);
    for (int q=0;q<4;q++){
      int n=lane+64*q;
      float4 w1=*(const float4*)&Wh[(size_t)(1+n)*4];
      float4 w2=*(const float4*)&Wh[(size_t)(1058+n)*4];
      float4 wu=*(const float4*)&Wh[(size_t)(257+n)*4];
      float4 wv=*(const float4*)&Wh[(size_t)(524+n)*4];
      float4 wh=*(const float4*)&Wh[(size_t)(791+n)*4];
      float zpn=zp[n], zln=zl[n], bn=b2[n];
      h.x += zpn*w1.x + zln*w2.x + bn*(wu.x+wv.x+wh.x);
      h.y += zpn*w1.y + zln*w2.y + bn*(wu.y+wv.y+wh.y);
      h.z += zpn*w1.z + zln*w2.z + bn*(wu.z+wv.z+wh.z);
      h.w += zpn*w1.w + zln*w2.w + bn*(wu.w+wv.w+wh.w);
    }
    if (lane<NAn){
      float4 wa=*(const float4*)&Wh[(size_t)(1047+lane)*4];
      float4 wb=*(const float4*)&Wh[(size_t)(1314+lane)*4];
      float aa=lm[lane], bb=lm[NAn+lane];
      h.x += aa*wa.x + bb*wb.x; h.y += aa*wa.y + bb*wb.y;
      h.z += aa*wa.z + bb*wb.z; h.w += aa*wa.w + bb*wb.w;
    }
    for (int off=32; off>0; off>>=1){
      h.x+=__shfl_xor(h.x,off); h.y+=__shfl_xor(h.y,off);
      h.z+=__shfl_xor(h.z,off); h.w+=__shfl_xor(h.w,off);
    }
    if (lane==0){
      hc4[0]=h.x+bh[0]; hc4[1]=h.y+bh[1]; hc4[2]=h.z+bh[2]; hc4[3]=h.w+bh[3];
    }
  }
}

// ================= decoder state + per-step logp (fused) =================

__global__ __launch_bounds__(256) void k_dc(const int* __restrict__ Sp, const int* __restrict__ dirs,
    const int* __restrict__ dird, const int* __restrict__ lab_idx,
    const float* __restrict__ Wd1, const float* __restrict__ bd1,
    const float* __restrict__ Pm, const int* __restrict__ rec,
    const float* __restrict__ m_arr, const float* __restrict__ e_arr,
    const float* __restrict__ hc4, const float* __restrict__ Wg, const float* __restrict__ Wh,
    float* __restrict__ out){
  int k = blockIdx.x;
  if (k > Sp[0]) return;
  __shared__ float sW[11*Dn];
  __shared__ float sP[Dn*PC];
  __shared__ float hT[Dn*N1];
  __shared__ float cnt[N1*11];
  __shared__ float y1[YN];
  __shared__ float za[YN];
  __shared__ float sdinv[N1];
  __shared__ int sdeg[N1];
  __shared__ int se[192], sd[192];
  __shared__ int slab[N1];
  __shared__ int srec[6*Tn];
  int tid=threadIdx.x;
  int ecnt = (k==0)?1:(2*k);
  int base = (k==0)?192:0;
  if (tid<N1){ sdeg[tid]=1; slab[tid]=lab_idx[tid]; }
  for (int i=tid;i<N1*11;i+=256) cnt[i]=0.f;
  for (int i=tid;i<11*Dn;i+=256) sW[i]=Wd1[i];
  for (int i=tid;i<Dn*PC;i+=256) sP[i]=Pm[i];
  for (int i=tid;i<6*Tn;i+=256) srec[i]=rec[i];
  __syncthreads();
  if (tid<ecnt){ se[tid]=dirs[base+tid]; sd[tid]=dird[base+tid]; atomicAdd(&sdeg[sd[tid]],1); }
  __syncthreads();
  if (tid<N1) sdinv[tid]=rsqrtf((float)sdeg[tid]);
  __syncthreads();
  if (tid<N1) cnt[tid*11+slab[tid]] = sdinv[tid];
  __syncthreads();
  if (tid<ecnt) atomicAdd(&cnt[sd[tid]*11+slab[se[tid]]], sdinv[se[tid]]);
  __syncthreads();
  { // h1 transposed, column c per thread
    int c=tid;
    float wreg[11];
    for (int a=0;a<11;a++) wreg[a]=sW[a*Dn+c];
    float b=bd1[c];
    for (int r=0;r<N1;r++){
      float s=0.f;
      for (int a=0;a<11;a++) s=fmaf(cnt[r*11+a], wreg[a], s);
      hT[c*N1+r]=fmaxf(sdinv[r]*s + b, 0.f);
    }
  }
  __syncthreads();
  for (int idx=tid; idx<YN; idx+=256){
    int r=idx/PC, j=idx-r*PC;
    float acc=0.f;
    for (int c=0;c<Dn;c++) acc=fmaf(hT[c*N1+r], sP[c*PC+j], acc);
    y1[idx]=acc;
    za[idx]=sdinv[r]*acc;
  }
  __syncthreads();
  for (int i=tid; i<ecnt*PC; i+=256){
    int e=i/PC, j=i-e*PC;
    atomicAdd(&za[sd[e]*PC+j], sdinv[se[e]]*y1[se[e]*PC+j]);
  }
  __syncthreads();
  for (int idx=tid; idx<YN; idx+=256){
    int r=idx/PC;
    za[idx]=sdinv[r]*za[idx];     // final Zc for this state, in LDS
  }
  __syncthreads();
  // ---- per-step logp for steps whose state index == k (wave 0 only) ----
  if (tid>=64) return;
  const int lane=tid;
  for (int t=0;t<Tn;t++){
    if (!srec[3*Tn+t] || srec[5*Tn+t]!=k) continue;
    const int u=srec[t], v=srec[Tn+t], bidx=srec[2*Tn+t], doe=srec[4*Tn+t];
    float g = -INFINITY;
    float4 hm = make_float4(0,0,0,0);
    if (lane<N1){
      const float* zrow = za + lane*PC;
      g = zrow[0] + Wg[780+slab[lane]] + m_arr[t*N1+lane];
      hm.x=zrow[9]; hm.y=zrow[10]; hm.z=zrow[11]; hm.w=zrow[12];
    }
    float gv = __shfl(g, v);
    float gM = g;
    for (int off=32; off>0; off>>=1) gM = fmaxf(gM, __shfl_xor(gM, off));
    float ex = (lane<N1)? expf(g-gM) : 0.f;
    float gS = ex;
    for (int off=32; off>0; off>>=1){
      gS += __shfl_xor(gS, off);
      hm.x+=__shfl_xor(hm.x,off); hm.y+=__shfl_xor(hm.y,off);
      hm.z+=__shfl_xor(hm.z,off); hm.w+=__shfl_xor(hm.w,off);
    }
    if (lane==0){
      float res = gv - gM - logf(gS);
      if (doe){
        const int lu=slab[u], lv=slab[v];
        const float tf=(float)k;
        float h[4];
        for (int j=0;j<4;j++){
          float hmj = (j==0)?hm.x:(j==1)?hm.y:(j==2)?hm.z:hm.w;
          h[j] = hc4[j] + tf*Wh[j] + Wh[(513+lu)*4+j] + Wh[(780+lv)*4+j]
               + za[u*PC+1+j] + za[v*PC+5+j] + hmj*(1.0f/49.0f) + e_arr[4*t+j];
        }
        float M=fmaxf(fmaxf(h[0],h[1]),fmaxf(h[2],h[3]));
        float se2=expf(h[0]-M)+expf(h[1]-M)+expf(h[2]-M)+expf(h[3]-M);
        float hb=(bidx==0)?h[0]:(bidx==1)?h[1]:(bidx==2)?h[2]:h[3];
        res += hb - M - logf(se2);
      }
      atomicAdd(out, res);
    }
  }
}

// ================= launch =================

extern "C" void kernel_launch(void* const* d_in, const int* in_sizes, int n_in,
                              void* d_out, int out_size, void* d_ws, size_t ws_size,
                              hipStream_t stream){
  const float* x_p      =(const float*)d_in[0];
  const int*   src_p    =(const int*)d_in[1];
  const int*   dst_p    =(const int*)d_in[2];
  const float* x_l_geom =(const float*)d_in[3];
  const int*   x_l_label=(const int*)d_in[4];
  const int*   src_l    =(const int*)d_in[5];
  const int*   dst_l    =(const int*)d_in[6];
  const int*   bfs_index=(const int*)d_in[7];
  const int*   bfs_bond =(const int*)d_in[8];
  const float* Wp1=(const float*)d_in[9];
  const float* bp1=(const float*)d_in[10];
  const float* Wp2=(const float*)d_in[11];
  const float* bp2=(const float*)d_in[12];
  const float* Wl1=(const float*)d_in[13];
  const float* bl1=(const float*)d_in[14];
  const float* Wl2=(const float*)d_in[15];
  const float* bl2=(const float*)d_in[16];
  const float* Wd1=(const float*)d_in[17];
  const float* bd1=(const float*)d_in[18];
  const float* Wd2=(const float*)d_in[19];
  const float* bd2=(const float*)d_in[20];
  const float* Wg =(const float*)d_in[23];
  const float* Wh =(const float*)d_in[25];
  const float* bh =(const float*)d_in[26];

  char* w=(char*)d_ws;
  size_t off=0;
  auto alloc=[&](size_t bytes)->char*{ char* p=w+off; off=(off+bytes+255)&~((size_t)255); return p; };
  // ---- contiguous zero-init region ----
  int*   deg    =(int*)alloc((size_t)NPn*4);
  float* odegw  =(float*)alloc((size_t)NPn*4);
  float* xagg   =(float*)alloc((size_t)NPn*16*4);
  float* zr     =(float*)alloc(Dn*4);
  size_t zero_span = off;
  // ---- rest ----
  float* zl_mean=(float*)alloc(Dn*4);
  float* Pm     =(float*)alloc(Dn*PC*4);
  float* hc4    =(float*)alloc(4*4);
  float* m_arr  =(float*)alloc((size_t)Tn*N1*4);
  float* e_arr  =(float*)alloc((size_t)Tn*4*4);
  int*   rec    =(int*)alloc((size_t)6*Tn*4);
  int*   dirs   =(int*)alloc(194*4);
  int*   dird   =(int*)alloc(194*4);
  int*   lab_idx=(int*)alloc(N1*4);
  float* lab_means=(float*)alloc(2*NAn*4);
  int*   Sval   =(int*)alloc(4);
  (void)in_sizes;(void)n_in;(void)ws_size;

  hipMemsetAsync(d_ws, 0, zero_span, stream);
  hipMemsetAsync(d_out, 0, (size_t)out_size*sizeof(float), stream);

  // A: sim (block 0) | lig (block 1) | pre (blocks 2..65) | deg (blocks 66..)
  kA<<<66 + EPn/256, 256, 0, stream>>>(
      dst_p, deg,
      x_l_label, bfs_index, bfs_bond, lab_idx, lab_means, dirs, dird, m_arr, e_arr, rec, Sval,
      x_l_geom, src_l, dst_l, Wl1, bl1, Wl2, bl2, zl_mean,
      Wd2, Wg, Wh, Pm);
  // pocket chain
  k_xagg<<<EPn*16/256,256,0,stream>>>(src_p,dst_p,x_p,deg,xagg,odegw);
  k_fuse<<<(NPn+CHN-1)/CHN,256,0,stream>>>(x_p,xagg,deg,odegw,Wp1,bp1,zr);
  k_zh<<<1,256,0,stream>>>(zr,Wp2,bp2,zl_mean,lab_means,bd2,Wh,bh,hc4);
  // decoder states + per-step logp
  k_dc<<<NSTATES,256,0,stream>>>(Sval,dirs,dird,lab_idx,Wd1,bd1,Pm,rec,m_arr,e_arr,hc4,Wg,Wh,(float*)d_out);
}

// Round 6
// 273.507 us; speedup vs baseline: 2.8224x; 1.0446x over previous
//
#include <hip/hip_runtime.h>
#include <math.h>

#define NPn 30000
#define EPn 480000
#define NLl 48
#define ELl 144
#define Tn 96
#define NAn 11
#define Dn 256
#define N1 49
#define NEGf (-1000000000.0f)
#define NSTATES 97
#define CHN 125
#define PC 13            // P columns: [g | u(4) | v(4) | hmean(4)]
#define YN (N1*PC)       // 637

// ================= kernel A: deg atomics | sim (phased) | lig | pre =================

__global__ __launch_bounds__(256) void kA(
    // deg part
    const int* __restrict__ dst_p, int* __restrict__ deg,
    // sim part
    const int* __restrict__ lab_in, const int* __restrict__ bfs_i, const int* __restrict__ bfs_b,
    int* __restrict__ lab_idx, float* __restrict__ lab_means,
    int* __restrict__ dirs, int* __restrict__ dird, float* __restrict__ m_arr,
    float* __restrict__ e_arr, int* __restrict__ rec, int* __restrict__ Sout,
    // lig part
    const float* __restrict__ xg, const int* __restrict__ srcl, const int* __restrict__ dstl,
    const float* __restrict__ Wl1, const float* __restrict__ bl1,
    const float* __restrict__ Wl2, const float* __restrict__ bl2, float* __restrict__ zl_mean,
    // pre part
    const float* __restrict__ Wd2, const float* __restrict__ Wg, const float* __restrict__ Wh,
    float* __restrict__ Pm){
  const int bid = blockIdx.x;
  const int tid = threadIdx.x;

  if (bid == 0){
    // ---------- phased control sim: no serial cross-lane latency chains ----------
    __shared__ int sv[Tn], sb[Tn];
    __shared__ int qarr[Tn+1];
    __shared__ int uArr[Tn], headA[Tn], doeA[Tn], popA[Tn], actA[Tn], timeA[Tn], eidxA[Tn];
    __shared__ float decA[Tn], valuA[Tn], valvA[Tn];
    __shared__ float baseB[Tn][N1];
    __shared__ int slab[N1];
    __shared__ int cntL[NAn];
    // preload + init (all 256 threads)
    if (tid < Tn){ sv[tid]=bfs_i[2*tid+1]; sb[tid]=bfs_b[tid]; }
    if (tid <= Tn) qarr[tid]=0;
    if (tid < NAn) cntL[tid]=0;
    if (tid < N1){ int l=(tid<NLl)? lab_in[tid] : (NAn-1); slab[tid]=l; lab_idx[tid]=l; }
    __syncthreads();
    if (tid < NLl) atomicAdd(&cntL[slab[tid]],1);
    if (tid == 0) qarr[0]=bfs_i[0];
    __syncthreads();
    if (tid < NAn){
      int c=cntL[tid];
      lab_means[tid]     = ((float)c + ((tid==NAn-1)?1.f:0.f))*(1.0f/49.0f);
      lab_means[NAn+tid] = (float)c*(1.0f/48.0f);
    }
    // ---- phase 0: scalar control recurrence (depends only on bfs) ----
    if (tid == 0){
      dirs[192]=qarr[0]; dird[192]=bfs_i[1];
      int head=0, tail=1, ec=0, timec=0;
      for (int t=0;t<Tn;t++){
        int v = sv[t];
        int active = (tail>head)?1:0;
        int is_stop = (v==NLl)?1:0;
        int pop = active & is_stop;
        int doe = active & (is_stop^1);
        headA[t]=head; actA[t]=active; doeA[t]=doe; popA[t]=pop; timeA[t]=timec;
        eidxA[t] = doe ? ec : -1;
        int bix = sb[t];
        decA[t] = (bix==0)?1.f:(bix==1)?2.f:(bix==2)?3.f:1.5f;
        if (doe && tail<=Tn) qarr[tail]=v;
        head+=pop; tail+=doe; ec+=2*doe; timec+=doe;
      }
      Sout[0]=ec/2;
    }
    __syncthreads();
    // ---- phase 0.5: u_t = Q[head_t], rec + dirs outputs (parallel over t) ----
    if (tid < Tn){
      int t=tid;
      int h=headA[t]; if (h>Tn) h=Tn;
      int u=qarr[h];
      uArr[t]=u;
      rec[t]=u; rec[Tn+t]=sv[t]; rec[2*Tn+t]=sb[t];
      rec[3*Tn+t]=actA[t]; rec[4*Tn+t]=doeA[t]; rec[5*Tn+t]=timeA[t];
      int ei=eidxA[t];
      if (ei>=0 && ei<192){
        int v=sv[t];
        dirs[ei]=u; dird[ei]=v; dirs[ei+1]=v; dird[ei+1]=u;
      }
    }
    __syncthreads();
    // ---- phase A: per-lane (node) val/closed/adj recurrence; broadcast reads only ----
    if (tid < 64){
      const int l = tid;
      int labv = (l<N1)? slab[l] : 0;
      float val;
      switch(labv){
        case 0: val=4.f; break; case 1: val=1.f; break; case 2: val=3.f; break;
        case 3: val=1.f; break; case 4: val=2.f; break; case 5: val=1.f; break;
        case 6: val=5.f; break; case 7: val=1.f; break; case 8: val=6.f; break;
        case 9: val=1.f; break; default: val=1000.f; break;
      }
      if (l>=N1) val=0.f;
      int closed=0;
      unsigned long long adjm=0ull;
      for (int t=0;t<Tn;t++){
        int u=uArr[t], v=sv[t];
        int doe=doeA[t], pop=popA[t];
        float base = (val<1.f || closed || ((adjm>>u)&1ull)) ? NEGf : 0.f;
        if (l==u) base=NEGf;
        if (l<N1) baseB[t][l]=base;
        if (l==u) valuA[t]=val;
        if (l==v) valvA[t]=val;
        if (doe){
          float dec=decA[t];
          if (l==u){ val-=dec; adjm |= (1ull<<v); }
          if (l==v){ val-=dec; adjm |= (1ull<<u); }
        }
        if (pop && l==u) closed=1;
      }
    }
    __syncthreads();
    // ---- phase B: finalize m/e outputs (4 waves x parallel over t) ----
    {
      const int lane=tid&63, wv=tid>>6;
      for (int t=wv; t<Tn; t+=4){
        float valu=valuA[t], valv=valvA[t];
        int v=sv[t], bix=sb[t];
        if (lane<N1){
          float mnou = (valu<1.f)? NEGf : baseB[t][lane];
          float m = mnou;
          if (lane==v) m=0.f;
          if (lane==NLl) m=0.f;
          m_arr[t*N1+lane]=m;
        }
        if (lane<4){
          float mnv = (valu<1.f)? NEGf : baseB[t][v];
          float mv = fminf(valu,valv);
          float e;
          if (mv<=0.f) e=NEGf;
          else if (mv<=1.f) e=((lane==1)||(lane==2))?NEGf:0.f;
          else if (mv<=2.f) e=(lane==2)?NEGf:0.f;
          else e=0.f;
          if (mnv <= NEGf*0.5f) e=NEGf;
          if (lane==bix) e=0.f;
          e_arr[t*4+lane]=e;
        }
      }
    }
    return;
  }

  if (bid == 1){
    // ---------- ligand GCN mean (collapsed) ----------
    __shared__ float sW[15*Dn];
    __shared__ float svec[NLl*4];
    __shared__ float scnt[NLl*11];
    __shared__ float ow[NLl];
    __shared__ float rs[Dn];
    __shared__ float sdinv[NLl];
    __shared__ int sdeg[NLl];
    __shared__ int ses[ELl], sed[ELl];
    __shared__ int slab2[NLl];
    if (tid<NLl){ sdeg[tid]=1; slab2[tid]=lab_in[tid]; }
    for (int i=tid;i<NLl*4;i+=256) svec[i]=0.f;
    for (int i=tid;i<NLl*11;i+=256) scnt[i]=0.f;
    for (int i=tid;i<15*Dn;i+=256) sW[i]=Wl1[i];
    __syncthreads();
    if (tid<ELl){ ses[tid]=srcl[tid]; sed[tid]=dstl[tid]; atomicAdd(&sdeg[dstl[tid]],1); }
    __syncthreads();
    if (tid<NLl) sdinv[tid]=rsqrtf((float)sdeg[tid]);
    __syncthreads();
    if (tid<NLl){
      float dv=sdinv[tid];
      ow[tid]=dv;
      for (int q=0;q<4;q++) svec[tid*4+q]=xg[tid*4+q]*dv;
      scnt[tid*11+slab2[tid]]=dv;
    }
    __syncthreads();
    if (tid<ELl){
      int s=ses[tid], d=sed[tid];
      float dvs=sdinv[s];
      for (int q=0;q<4;q++) atomicAdd(&svec[d*4+q], xg[s*4+q]*dvs);
      atomicAdd(&scnt[d*11+slab2[s]], dvs);
      atomicAdd(&ow[s], sdinv[d]);
    }
    __syncthreads();
    {
      int c=tid;
      float b=bl1[c];
      float rsum=0.f;
      for (int d=0;d<NLl;d++){
        float a=0.f;
        for (int q=0;q<4;q++)  a=fmaf(svec[d*4+q], sW[q*Dn+c], a);
        for (int aa=0;aa<11;aa++) a=fmaf(scnt[d*11+aa], sW[(4+aa)*Dn+c], a);
        float h=fmaxf(sdinv[d]*a + b, 0.f);
        rsum = fmaf(sdinv[d]*ow[d], h, rsum);
      }
      rs[c]=rsum*(1.0f/48.0f);
    }
    __syncthreads();
    {
      int c=tid;
      float a=0.f;
      for (int k=0;k<Dn;k++) a=fmaf(rs[k], Wl2[(size_t)k*Dn+c], a);
      zl_mean[c]=a+bl2[c];
    }
    return;
  }

  if (bid < 2+64){
    // ---------- P = Wd2 @ [wg2 | Whu | Whv | Whh] : one k per wave ----------
    const int lane = tid&63, wv = tid>>6;
    const int k = (bid-2)*4 + wv;
    float pg=0.f;
    float4 pu=make_float4(0,0,0,0), pv=make_float4(0,0,0,0), ph=make_float4(0,0,0,0);
    for (int q=0;q<4;q++){
      int n = lane + 64*q;
      float w = Wd2[(size_t)k*Dn+n];
      pg = fmaf(w, Wg[524+n], pg);
      float4 a=*(const float4*)&Wh[(size_t)(257+n)*4];
      float4 b=*(const float4*)&Wh[(size_t)(524+n)*4];
      float4 c=*(const float4*)&Wh[(size_t)(791+n)*4];
      pu.x=fmaf(w,a.x,pu.x); pu.y=fmaf(w,a.y,pu.y); pu.z=fmaf(w,a.z,pu.z); pu.w=fmaf(w,a.w,pu.w);
      pv.x=fmaf(w,b.x,pv.x); pv.y=fmaf(w,b.y,pv.y); pv.z=fmaf(w,b.z,pv.z); pv.w=fmaf(w,b.w,pv.w);
      ph.x=fmaf(w,c.x,ph.x); ph.y=fmaf(w,c.y,ph.y); ph.z=fmaf(w,c.z,ph.z); ph.w=fmaf(w,c.w,ph.w);
    }
    for (int off=32; off>0; off>>=1){
      pg += __shfl_xor(pg,off);
      pu.x+=__shfl_xor(pu.x,off); pu.y+=__shfl_xor(pu.y,off); pu.z+=__shfl_xor(pu.z,off); pu.w+=__shfl_xor(pu.w,off);
      pv.x+=__shfl_xor(pv.x,off); pv.y+=__shfl_xor(pv.y,off); pv.z+=__shfl_xor(pv.z,off); pv.w+=__shfl_xor(pv.w,off);
      ph.x+=__shfl_xor(ph.x,off); ph.y+=__shfl_xor(ph.y,off); ph.z+=__shfl_xor(ph.z,off); ph.w+=__shfl_xor(ph.w,off);
    }
    if (lane==0){
      float* o = Pm + k*PC;
      o[0]=pg; o[1]=pu.x; o[2]=pu.y; o[3]=pu.z; o[4]=pu.w;
      o[5]=pv.x; o[6]=pv.y; o[7]=pv.z; o[8]=pv.w;
      o[9]=ph.x; o[10]=ph.y; o[11]=ph.z; o[12]=ph.w;
    }
    return;
  }

  // ---------- deg atomics ----------
  {
    int e = (bid-66)*256 + tid;
    if (e < EPn) atomicAdd(&deg[dst_p[e]], 1);
  }
}

// ================= pocket GCN (collapsed) =================

// lanes c<15: xagg[dst][c] += x_p[src][c]*dinv[src];  lane c==15: odegw[src] += dinv[dst]
__global__ void k_xagg(const int* __restrict__ src, const int* __restrict__ dst,
                       const float* __restrict__ xp, const int* __restrict__ deg,
                       float* __restrict__ xagg, float* __restrict__ odegw){
  int g = blockIdx.x*blockDim.x + threadIdx.x;
  int e = g>>4, c = g&15;
  if (e >= EPn) return;
  int s = src[e], d = dst[e];
  if (c < 15){
    float dvs = rsqrtf((float)(deg[s]+1));
    atomicAdd(&xagg[d*16+c], xp[s*15+c]*dvs);
  } else {
    float dvd = rsqrtf((float)(deg[d]+1));
    atomicAdd(&odegw[s], dvd);
  }
}

__global__ __launch_bounds__(256) void k_fuse(const float* __restrict__ xp, const float* __restrict__ xagg,
    const int* __restrict__ deg, const float* __restrict__ odegw,
    const float* __restrict__ Wp1, const float* __restrict__ bp1, float* __restrict__ zr){
  __shared__ float sx[CHN][16];
  __shared__ float sc[CHN];
  int tid = threadIdx.x;
  int base = blockIdx.x*CHN;
  float wcol[15];
  for (int k=0;k<15;k++) wcol[k]=Wp1[k*Dn+tid];
  float b = bp1[tid];
  for (int i=tid;i<CHN*16;i+=256){
    int n = base+(i>>4), c = i&15;
    float v = 0.f;
    if (n<NPn && c<15){
      float dv = rsqrtf((float)(deg[n]+1));
      v = (xagg[n*16+c] + xp[n*15+c]*dv)*dv;
    }
    sx[i>>4][i&15]=v;
  }
  for (int i=tid;i<CHN;i+=256){
    int n = base+i;
    float dv = (n<NPn)? rsqrtf((float)(deg[n]+1)) : 0.f;
    sc[i] = (n<NPn)? dv*(odegw[n]+dv) : 0.f;
  }
  __syncthreads();
  float acc = 0.f;
  int lim = (NPn-base < CHN)? (NPn-base) : CHN;
  for (int i=0;i<lim;i++){
    float d0 = b;
    for (int k=0;k<15;k++) d0 = fmaf(sx[i][k], wcol[k], d0);
    acc = fmaf(sc[i], fmaxf(d0,0.f), acc);
  }
  atomicAdd(&zr[tid], acc);
}

// ================= z_pocket GEMV + hconst (fused) =================

__global__ __launch_bounds__(256) void k_zh(const float* __restrict__ zr, const float* __restrict__ Wp2,
    const float* __restrict__ bp2, const float* __restrict__ zl, const float* __restrict__ lm,
    const float* __restrict__ b2, const float* __restrict__ Wh, const float* __restrict__ bh,
    float* __restrict__ hc4){
  __shared__ float sr[Dn];
  __shared__ float zp[Dn];
  int tid=threadIdx.x;
  sr[tid]=zr[tid]*(1.0f/30000.0f);
  __syncthreads();
  float a=0.f;
  for (int k=0;k<Dn;k++) a=fmaf(sr[k],Wp2[(size_t)k*Dn+tid],a);
  zp[tid]=a+bp2[tid];
  __syncthreads();
  if (tid<64){
    int lane=tid;
    float4 h=make_float4(0,0,0,0);
    for (int q=0;q<4;q++){
      int n=lane+64*q;
      float4 w1=*(const float4*)&Wh[(size_t)(1+n)*4];
      float4 w2=*(const float4*)&Wh[(size_t)(1058+n)*4];
      float4 wu=*(const float4*)&Wh[(size_t)(257+n)*4];
      float4 wv=*(const float4*)&Wh[(size_t)(524+n)*4];
      float4 wh=*(const float4*)&Wh[(size_t)(791+n)*4];
      float zpn=zp[n], zln=zl[n], bn=b2[n];
      h.x += zpn*w1.x + zln*w2.x + bn*(wu.x+wv.x+wh.x);
      h.y += zpn*w1.y + zln*w2.y + bn*(wu.y+wv.y+wh.y);
      h.z += zpn*w1.z + zln*w2.z + bn*(wu.z+wv.z+wh.z);
      h.w += zpn*w1.w + zln*w2.w + bn*(wu.w+wv.w+wh.w);
    }
    if (lane<NAn){
      float4 wa=*(const float4*)&Wh[(size_t)(1047+lane)*4];
      float4 wb=*(const float4*)&Wh[(size_t)(1314+lane)*4];
      float aa=lm[lane], bb=lm[NAn+lane];
      h.x += aa*wa.x + bb*wb.x; h.y += aa*wa.y + bb*wb.y;
      h.z += aa*wa.z + bb*wb.z; h.w += aa*wa.w + bb*wb.w;
    }
    for (int off=32; off>0; off>>=1){
      h.x+=__shfl_xor(h.x,off); h.y+=__shfl_xor(h.y,off);
      h.z+=__shfl_xor(h.z,off); h.w+=__shfl_xor(h.w,off);
    }
    if (lane==0){
      hc4[0]=h.x+bh[0]; hc4[1]=h.y+bh[1]; hc4[2]=h.z+bh[2]; hc4[3]=h.w+bh[3];
    }
  }
}

// ================= decoder state + per-step logp (fused) =================

__global__ __launch_bounds__(256) void k_dc(const int* __restrict__ Sp, const int* __restrict__ dirs,
    const int* __restrict__ dird, const int* __restrict__ lab_idx,
    const float* __restrict__ Wd1, const float* __restrict__ bd1,
    const float* __restrict__ Pm, const int* __restrict__ rec,
    const float* __restrict__ m_arr, const float* __restrict__ e_arr,
    const float* __restrict__ hc4, const float* __restrict__ Wg, const float* __restrict__ Wh,
    float* __restrict__ out){
  int k = blockIdx.x;
  if (k > Sp[0]) return;
  __shared__ float sW[11*Dn];
  __shared__ float sP[Dn*PC];
  __shared__ float hT[Dn*N1];
  __shared__ float cnt[N1*11];
  __shared__ float y1[YN];
  __shared__ float za[YN];
  __shared__ float sdinv[N1];
  __shared__ int sdeg[N1];
  __shared__ int se[192], sd[192];
  __shared__ int slab[N1];
  __shared__ int srec[6*Tn];
  int tid=threadIdx.x;
  int ecnt = (k==0)?1:(2*k);
  int base = (k==0)?192:0;
  if (tid<N1){ sdeg[tid]=1; slab[tid]=lab_idx[tid]; }
  for (int i=tid;i<N1*11;i+=256) cnt[i]=0.f;
  for (int i=tid;i<11*Dn;i+=256) sW[i]=Wd1[i];
  for (int i=tid;i<Dn*PC;i+=256) sP[i]=Pm[i];
  for (int i=tid;i<6*Tn;i+=256) srec[i]=rec[i];
  __syncthreads();
  if (tid<ecnt){ se[tid]=dirs[base+tid]; sd[tid]=dird[base+tid]; atomicAdd(&sdeg[sd[tid]],1); }
  __syncthreads();
  if (tid<N1) sdinv[tid]=rsqrtf((float)sdeg[tid]);
  __syncthreads();
  if (tid<N1) cnt[tid*11+slab[tid]] = sdinv[tid];
  __syncthreads();
  if (tid<ecnt) atomicAdd(&cnt[sd[tid]*11+slab[se[tid]]], sdinv[se[tid]]);
  __syncthreads();
  { // h1 transposed, column c per thread
    int c=tid;
    float wreg[11];
    for (int a=0;a<11;a++) wreg[a]=sW[a*Dn+c];
    float b=bd1[c];
    for (int r=0;r<N1;r++){
      float s=0.f;
      for (int a=0;a<11;a++) s=fmaf(cnt[r*11+a], wreg[a], s);
      hT[c*N1+r]=fmaxf(sdinv[r]*s + b, 0.f);
    }
  }
  __syncthreads();
  for (int idx=tid; idx<YN; idx+=256){
    int r=idx/PC, j=idx-r*PC;
    float acc=0.f;
    for (int c=0;c<Dn;c++) acc=fmaf(hT[c*N1+r], sP[c*PC+j], acc);
    y1[idx]=acc;
    za[idx]=sdinv[r]*acc;
  }
  __syncthreads();
  for (int i=tid; i<ecnt*PC; i+=256){
    int e=i/PC, j=i-e*PC;
    atomicAdd(&za[sd[e]*PC+j], sdinv[se[e]]*y1[se[e]*PC+j]);
  }
  __syncthreads();
  for (int idx=tid; idx<YN; idx+=256){
    int r=idx/PC;
    za[idx]=sdinv[r]*za[idx];     // final Zc for this state, in LDS
  }
  __syncthreads();
  // ---- per-step logp for steps whose state index == k (wave 0 only) ----
  if (tid>=64) return;
  const int lane=tid;
  for (int t=0;t<Tn;t++){
    if (!srec[3*Tn+t] || srec[5*Tn+t]!=k) continue;
    const int u=srec[t], v=srec[Tn+t], bidx=srec[2*Tn+t], doe=srec[4*Tn+t];
    float g = -INFINITY;
    float4 hm = make_float4(0,0,0,0);
    if (lane<N1){
      const float* zrow = za + lane*PC;
      g = zrow[0] + Wg[780+slab[lane]] + m_arr[t*N1+lane];
      hm.x=zrow[9]; hm.y=zrow[10]; hm.z=zrow[11]; hm.w=zrow[12];
    }
    float gv = __shfl(g, v);
    float gM = g;
    for (int off=32; off>0; off>>=1) gM = fmaxf(gM, __shfl_xor(gM, off));
    float ex = (lane<N1)? expf(g-gM) : 0.f;
    float gS = ex;
    for (int off=32; off>0; off>>=1){
      gS += __shfl_xor(gS, off);
      hm.x+=__shfl_xor(hm.x,off); hm.y+=__shfl_xor(hm.y,off);
      hm.z+=__shfl_xor(hm.z,off); hm.w+=__shfl_xor(hm.w,off);
    }
    if (lane==0){
      float res = gv - gM - logf(gS);
      if (doe){
        const int lu=slab[u], lv=slab[v];
        const float tf=(float)k;
        float h[4];
        for (int j=0;j<4;j++){
          float hmj = (j==0)?hm.x:(j==1)?hm.y:(j==2)?hm.z:hm.w;
          h[j] = hc4[j] + tf*Wh[j] + Wh[(513+lu)*4+j] + Wh[(780+lv)*4+j]
               + za[u*PC+1+j] + za[v*PC+5+j] + hmj*(1.0f/49.0f) + e_arr[4*t+j];
        }
        float M=fmaxf(fmaxf(h[0],h[1]),fmaxf(h[2],h[3]));
        float se2=expf(h[0]-M)+expf(h[1]-M)+expf(h[2]-M)+expf(h[3]-M);
        float hb=(bidx==0)?h[0]:(bidx==1)?h[1]:(bidx==2)?h[2]:h[3];
        res += hb - M - logf(se2);
      }
      atomicAdd(out, res);
    }
  }
}

// ================= launch =================

extern "C" void kernel_launch(void* const* d_in, const int* in_sizes, int n_in,
                              void* d_out, int out_size, void* d_ws, size_t ws_size,
                              hipStream_t stream){
  const float* x_p      =(const float*)d_in[0];
  const int*   src_p    =(const int*)d_in[1];
  const int*   dst_p    =(const int*)d_in[2];
  const float* x_l_geom =(const float*)d_in[3];
  const int*   x_l_label=(const int*)d_in[4];
  const int*   src_l    =(const int*)d_in[5];
  const int*   dst_l    =(const int*)d_in[6];
  const int*   bfs_index=(const int*)d_in[7];
  const int*   bfs_bond =(const int*)d_in[8];
  const float* Wp1=(const float*)d_in[9];
  const float* bp1=(const float*)d_in[10];
  const float* Wp2=(const float*)d_in[11];
  const float* bp2=(const float*)d_in[12];
  const float* Wl1=(const float*)d_in[13];
  const float* bl1=(const float*)d_in[14];
  const float* Wl2=(const float*)d_in[15];
  const float* bl2=(const float*)d_in[16];
  const float* Wd1=(const float*)d_in[17];
  const float* bd1=(const float*)d_in[18];
  const float* Wd2=(const float*)d_in[19];
  const float* bd2=(const float*)d_in[20];
  const float* Wg =(const float*)d_in[23];
  const float* Wh =(const float*)d_in[25];
  const float* bh =(const float*)d_in[26];

  char* w=(char*)d_ws;
  size_t off=0;
  auto alloc=[&](size_t bytes)->char*{ char* p=w+off; off=(off+bytes+255)&~((size_t)255); return p; };
  // ---- contiguous zero-init region ----
  int*   deg    =(int*)alloc((size_t)NPn*4);
  float* odegw  =(float*)alloc((size_t)NPn*4);
  float* xagg   =(float*)alloc((size_t)NPn*16*4);
  float* zr     =(float*)alloc(Dn*4);
  size_t zero_span = off;
  // ---- rest ----
  float* zl_mean=(float*)alloc(Dn*4);
  float* Pm     =(float*)alloc(Dn*PC*4);
  float* hc4    =(float*)alloc(4*4);
  float* m_arr  =(float*)alloc((size_t)Tn*N1*4);
  float* e_arr  =(float*)alloc((size_t)Tn*4*4);
  int*   rec    =(int*)alloc((size_t)6*Tn*4);
  int*   dirs   =(int*)alloc(194*4);
  int*   dird   =(int*)alloc(194*4);
  int*   lab_idx=(int*)alloc(N1*4);
  float* lab_means=(float*)alloc(2*NAn*4);
  int*   Sval   =(int*)alloc(4);
  (void)in_sizes;(void)n_in;(void)ws_size;

  hipMemsetAsync(d_ws, 0, zero_span, stream);
  hipMemsetAsync(d_out, 0, (size_t)out_size*sizeof(float), stream);

  // A: sim (block 0) | lig (block 1) | pre (blocks 2..65) | deg (blocks 66..)
  kA<<<66 + EPn/256, 256, 0, stream>>>(
      dst_p, deg,
      x_l_label, bfs_index, bfs_bond, lab_idx, lab_means, dirs, dird, m_arr, e_arr, rec, Sval,
      x_l_geom, src_l, dst_l, Wl1, bl1, Wl2, bl2, zl_mean,
      Wd2, Wg, Wh, Pm);
  // pocket chain
  k_xagg<<<EPn*16/256,256,0,stream>>>(src_p,dst_p,x_p,deg,xagg,odegw);
  k_fuse<<<(NPn+CHN-1)/CHN,256,0,stream>>>(x_p,xagg,deg,odegw,Wp1,bp1,zr);
  k_zh<<<1,256,0,stream>>>(zr,Wp2,bp2,zl_mean,lab_means,bd2,Wh,bh,hc4);
  // decoder states + per-step logp
  k_dc<<<NSTATES,256,0,stream>>>(Sval,dirs,dird,lab_idx,Wd1,bd1,Pm,rec,m_arr,e_arr,hc4,Wg,Wh,(float*)d_out);
}